// Round 13
// baseline (1017.661 us; speedup 1.0000x reference)
//
#include <hip/hip_runtime.h>
#include <stdint.h>

#define DEVFN __device__ __forceinline__

typedef __attribute__((ext_vector_type(8))) short short8;
typedef __attribute__((ext_vector_type(4))) short short4v;
typedef __attribute__((ext_vector_type(4))) float floatx4;
typedef __attribute__((ext_vector_type(16))) float floatx16;
typedef __attribute__((ext_vector_type(4))) float vfloat4;
typedef __attribute__((ext_vector_type(2))) unsigned int uint2v;
typedef __attribute__((ext_vector_type(4))) unsigned int uint4v;

#define MFMA_BF16(a,b,c) __builtin_amdgcn_mfma_f32_16x16x32_bf16((a),(b),(c),0,0,0)
#define MFMA32_BF16(a,b,c) __builtin_amdgcn_mfma_f32_32x32x16_bf16((a),(b),(c),0,0,0)
#define GL2LDS(g,l) __builtin_amdgcn_global_load_lds((const __attribute__((address_space(1))) void*)(g), (__attribute__((address_space(3))) void*)(l), 16, 0, 0)

DEVFN unsigned short f2bf(float f){
  unsigned u = __float_as_uint(f);
  u = (u + 0x7fffu + ((u >> 16) & 1u)) >> 16;
  return (unsigned short)u;
}

DEVFN unsigned cvtpk_bf16(float lo, float hi){
  unsigned r;
  asm("v_cvt_pk_bf16_f32 %0, %1, %2" : "=v"(r) : "v"(lo), "v"(hi));
  return r;
}

// ---------------- mask dtype detection ----------------
__global__ void detect_kernel(const unsigned char* m, unsigned int* flag){
  if (threadIdx.x == 0) *flag = 0u;
  __syncthreads();
  int any = 0;
  for (int i = threadIdx.x; i < 4096; i += 256)
    if ((i & 3) != 0 && m[i]) any = 1;
  if (any) atomicOr(flag, 1u);
}

// ---------------- prep (small): x->bf16, weightsT->bf16 (Q pre-scaled) ----------------
__global__ void prep_small_kernel(const float* __restrict__ x, const float* __restrict__ wg,
                                  const float* __restrict__ wq, const float* __restrict__ wo,
                                  unsigned short* __restrict__ xbf, unsigned short* __restrict__ wcat,
                                  unsigned short* __restrict__ woutT)
{
  int bid = blockIdx.x, tid = threadIdx.x;
  if (bid < 8192) {                               // x -> bf16
    int i = (bid*256 + tid)*4;
    vfloat4 v = *(const vfloat4*)&x[i];
    short4v c; c[0]=(short)f2bf(v[0]); c[1]=(short)f2bf(v[1]); c[2]=(short)f2bf(v[2]); c[3]=(short)f2bf(v[3]);
    *(short4v*)&xbf[i] = c;
  } else if (bid < 12288) {                       // WcatT (Q cols pre-scaled by 0.125*log2e)
    int i = (bid - 8192)*256 + tid;
    int k = i & 511, c = i >> 9;
    float v = (c < 512) ? wg[k*512 + c] : wq[k*1536 + (c - 512)];
    if (c >= 512 && c < 1024) v *= 0.18033688f;
    wcat[c*512 + k] = (unsigned short)f2bf(v);
  } else {                                        // WoutT
    int i = (bid - 12288)*256 + tid;
    int k = i & 1023, n2 = i >> 10;
    woutT[n2*1024 + k] = (unsigned short)f2bf(wo[k*512 + n2]);
  }
}

// ---------------- prep (full, fallback path only) ----------------
__global__ void prep_full_kernel(const float* __restrict__ x, const float* __restrict__ wg,
                                 const float* __restrict__ wq, const float* __restrict__ wo,
                                 const void* __restrict__ mask, const unsigned* __restrict__ flag,
                                 unsigned short* __restrict__ xbf, unsigned short* __restrict__ wcat,
                                 unsigned short* __restrict__ woutT, unsigned* __restrict__ mp)
{
  int bid = blockIdx.x, tid = threadIdx.x;
  if (bid < 8192) {
    int i = (bid*256 + tid)*4;
    vfloat4 v = *(const vfloat4*)&x[i];
    short4v c; c[0]=(short)f2bf(v[0]); c[1]=(short)f2bf(v[1]); c[2]=(short)f2bf(v[2]); c[3]=(short)f2bf(v[3]);
    *(short4v*)&xbf[i] = c;
  } else if (bid < 12288) {
    int i = (bid - 8192)*256 + tid;
    int k = i & 511, c = i >> 9;
    float v = (c < 512) ? wg[k*512 + c] : wq[k*1536 + (c - 512)];
    if (c >= 512 && c < 1024) v *= 0.18033688f;
    wcat[c*512 + k] = (unsigned short)f2bf(v);
  } else if (bid < 14336) {
    int i = (bid - 12288)*256 + tid;
    int k = i & 1023, n2 = i >> 10;
    woutT[n2*1024 + k] = (unsigned short)f2bf(wo[k*512 + n2]);
  } else {                                        // mask bit-pack
    int j = bid - 14336;
    int e = j*256 + tid;
    int v;
    if (*flag) v = ((const unsigned char*)mask)[e];
    else       v = ((const int*)mask)[e];
    unsigned long long ball = __ballot(v != 0);
    int base = e & ~63;
    int lane = tid & 63;
    if (lane == 0)  mp[(base >> 5) + 0] = (unsigned)(ball & 0xffffffffull);
    if (lane == 32) mp[(base >> 5) + 1] = (unsigned)(ball >> 32);
  }
}

// ---------------- shared 128x128 BK=32 bf16 K-loop (m97 structure) ----------------
DEVFN void gemm_kloop_bf16(const unsigned short* Ag, int lda,
                           const unsigned short* Bg, int ldb, int K,
                           short* As, short* Bs, int w, int l,
                           floatx4 (&acc)[4][4])
{
  const int wr = (w >> 1)*64, wc = (w & 1)*64;
  for (int k0 = 0; k0 < K; k0 += 32) {
    __syncthreads();
#pragma unroll
    for (int i = 0; i < 2; i++) {
      int id = (w*2 + i)*64 + l;
      int row = id >> 2, part = id & 3;
      GL2LDS(Ag + row*lda + k0 + part*8, As + (w*2 + i)*512);
      GL2LDS(Bg + row*ldb + k0 + part*8, Bs + (w*2 + i)*512);
    }
    __syncthreads();
    short8 af[4], bfr[4];
#pragma unroll
    for (int t = 0; t < 4; t++) {
      af[t]  = *(const short8*)&As[(wr + t*16 + (l & 15))*32 + ((l >> 4) << 3)];
      bfr[t] = *(const short8*)&Bs[(wc + t*16 + (l & 15))*32 + ((l >> 4) << 3)];
    }
#pragma unroll
    for (int a2 = 0; a2 < 4; a2++)
#pragma unroll
      for (int b2 = 0; b2 < 4; b2++)
        acc[a2][b2] = MFMA_BF16(af[a2], bfr[b2], acc[a2][b2]);
  }
}

// ---------------- GEMM-AB (+ pipelined BW blocks): xgT/Q/K/VT ; mask pack ; adj->bf16 ----------------
__global__ __launch_bounds__(256, 2)
void gemm_ab_kernel(const unsigned short* __restrict__ xbf, const unsigned short* __restrict__ wcat,
                    unsigned short* __restrict__ xgT, unsigned short* __restrict__ Qo,
                    unsigned short* __restrict__ Ko, unsigned short* __restrict__ VTo,
                    const void* __restrict__ mask, const unsigned* __restrict__ flag,
                    const float* __restrict__ adj,
                    unsigned* __restrict__ mp, unsigned short* __restrict__ adjb,
                    int mode)
{
  __shared__ short lds[16384];
  int tid = threadIdx.x, w = tid >> 6, l = tid & 63;
  int bid = blockIdx.x;

  int gemmid;
  if (mode) {
    int r11 = bid % 11, g11 = bid / 11;
    if (r11 != 0) {
      int bw = g11*10 + (r11 - 1);                // 0..20479
      if (bw < 16384) {
        unsigned fl = *flag;
        int lane = tid & 63;
        int vv[8];
        if (fl) {
          const unsigned char* m8 = (const unsigned char*)mask;
#pragma unroll
          for (int j = 0; j < 8; j++) vv[j] = m8[(bw*8 + j)*256 + tid];
        } else {
          const int* m32 = (const int*)mask;
#pragma unroll
          for (int j = 0; j < 8; j++) vv[j] = m32[(bw*8 + j)*256 + tid];
        }
#pragma unroll
        for (int j = 0; j < 8; j++) {
          unsigned long long ball = __ballot(vv[j] != 0);
          int e = (bw*8 + j)*256 + tid;
          int base = e & ~63;
          if (lane == 0)  mp[(base >> 5) + 0] = (unsigned)(ball & 0xffffffffull);
          if (lane == 32) mp[(base >> 5) + 1] = (unsigned)(ball >> 32);
        }
      } else {
        int ab = bw - 16384;
        vfloat4 vv[8];
#pragma unroll
        for (int j = 0; j < 8; j++)
          vv[j] = *(const vfloat4*)&adj[((ab*8 + j)*256 + tid)*4];
#pragma unroll
        for (int j = 0; j < 8; j++) {
          short4v c; c[0]=(short)f2bf(vv[j][0]); c[1]=(short)f2bf(vv[j][1]);
          c[2]=(short)f2bf(vv[j][2]); c[3]=(short)f2bf(vv[j][3]);
          *(short4v*)&adjb[((ab*8 + j)*256 + tid)*4] = c;
        }
      }
      return;
    }
    gemmid = g11;                                 // 0..2047
  } else {
    gemmid = bid;
  }

  int xcd = gemmid & 7, slot = gemmid >> 3;
  int p  = xcd + ((slot >> 4) << 3);
  int nt = slot & 15;
  int rows0 = p*128, cols0 = nt*128;

  floatx4 acc[4][4];
  const floatx4 zf = {0.f, 0.f, 0.f, 0.f};
#pragma unroll
  for (int a2 = 0; a2 < 4; a2++)
#pragma unroll
    for (int b2 = 0; b2 < 4; b2++) acc[a2][b2] = zf;

  gemm_kloop_bf16(xbf + rows0*512, 512, wcat + cols0*512, 512, 512,
                  lds, lds + 4096, w, l, acc);
  __syncthreads();

  int wr = (w >> 1)*64, wc = (w & 1)*64;
  int b = p >> 4;
  int n0 = (p & 15)*128 + wr;
  int gc0 = cols0 + wc;

  if (nt < 4 || nt >= 12) {
    short* T = lds + w*4096;
#pragma unroll
    for (int mi = 0; mi < 4; mi++)
#pragma unroll
      for (int bi = 0; bi < 4; bi++)
#pragma unroll
        for (int r = 0; r < 4; r++) {
          int rl = mi*16 + ((l >> 4) << 2) + r;
          int cl = bi*16 + (l & 15);
          T[cl*64 + ((((rl >> 3) ^ (cl & 7))) << 3) + (rl & 7)] = (short)f2bf(acc[mi][bi][r]);
        }
#pragma unroll
    for (int i = 0; i < 8; i++) {
      int chunk = i*64 + l;
      int c = chunk >> 3, s = chunk & 7;
      short8 v = *(const short8*)&T[c*64 + ((s ^ (c & 7)) << 3)];
      int rowstart = n0 + s*8;
      if (nt < 4) {
        int d = gc0 + c;
        *(short8*)&xgT[(b*512 + d)*2048 + rowstart] = v;
      } else {
        int vc = gc0 + c - 1536;
        int hh = vc >> 6, dd = vc & 63;
        *(short8*)&VTo[((b*8 + hh)*64 + dd)*2048 + rowstart] = v;
      }
    }
  } else {
    unsigned short* dst = (nt < 8) ? Qo : Ko;
    int cbase = gc0 - ((nt < 8) ? 512 : 1024);
    int hh = cbase >> 6;
#pragma unroll
    for (int mi = 0; mi < 4; mi++)
#pragma unroll
      for (int bi = 0; bi < 4; bi++)
#pragma unroll
        for (int r = 0; r < 4; r++) {
          int rowg = n0 + mi*16 + ((l >> 4) << 2) + r;
          int dd = bi*16 + (l & 15);
          dst[((b*8 + hh)*2048 + rowg)*64 + dd] = (unsigned short)f2bf(acc[mi][bi][r]);
        }
  }
}

// ---------------- GEMM-C (fp32 fallback, original) ----------------
__global__ __launch_bounds__(256, 2)
void gemm_c_f32_kernel(const float* __restrict__ adj, const unsigned short* __restrict__ xgT,
                       unsigned short* __restrict__ cat)
{
  __shared__ short lds[8192];
  int tid = threadIdx.x, w = tid >> 6, l = tid & 63;
  int bid = blockIdx.x;
  int xcd = bid & 7, slot = bid >> 3;
  int p  = xcd + ((slot >> 2) << 3);
  int nt = slot & 3;
  int b = p >> 4, mt = p & 15;
  int rows0 = mt*128, cols0 = nt*128;
  const float* Ag = adj + (size_t)b*2048*2048 + (size_t)rows0*2048;
  const unsigned short* Bg = xgT + (b*512 + cols0)*2048;

  floatx4 acc[4][4];
  const floatx4 zf = {0.f, 0.f, 0.f, 0.f};
#pragma unroll
  for (int a2 = 0; a2 < 4; a2++)
#pragma unroll
    for (int b2 = 0; b2 < 4; b2++) acc[a2][b2] = zf;

  const int wr = (w >> 1)*64, wc = (w & 1)*64;
  for (int k0 = 0; k0 < 2048; k0 += 32) {
    __syncthreads();
#pragma unroll
    for (int i = 0; i < 4; i++) {
      int id = (w*4 + i)*64 + l;
      int row = id >> 3, part = id & 7;
      vfloat4 v = *(const vfloat4*)&Ag[row*2048 + k0 + part*4];
      short4v c4; c4[0]=(short)f2bf(v[0]); c4[1]=(short)f2bf(v[1]); c4[2]=(short)f2bf(v[2]); c4[3]=(short)f2bf(v[3]);
      *(short4v*)&lds[row*32 + part*4] = c4;
    }
#pragma unroll
    for (int i = 0; i < 2; i++) {
      int id = (w*2 + i)*64 + l;
      int row = id >> 2, part = id & 3;
      GL2LDS(Bg + row*2048 + k0 + part*8, lds + 4096 + (w*2 + i)*512);
    }
    __syncthreads();
    short8 af[4], bfr[4];
#pragma unroll
    for (int t = 0; t < 4; t++) {
      af[t]  = *(const short8*)&lds[(wr + t*16 + (l & 15))*32 + ((l >> 4) << 3)];
      bfr[t] = *(const short8*)&lds[4096 + (wc + t*16 + (l & 15))*32 + ((l >> 4) << 3)];
    }
#pragma unroll
    for (int a2 = 0; a2 < 4; a2++)
#pragma unroll
      for (int b2 = 0; b2 < 4; b2++)
        acc[a2][b2] = MFMA_BF16(af[a2], bfr[b2], acc[a2][b2]);
  }

#pragma unroll
  for (int mi = 0; mi < 4; mi++)
#pragma unroll
    for (int bi = 0; bi < 4; bi++)
#pragma unroll
      for (int r = 0; r < 4; r++) {
        int rowg = b*2048 + rows0 + wr + mi*16 + ((l >> 4) << 2) + r;
        int col  = 512 + cols0 + wc + bi*16 + (l & 15);
        cat[rowg*1024 + col] = (unsigned short)f2bf(acc[mi][bi][r]);
      }
}

// ---------------- attn tile body (v10: K dbuf + V single-buffer, two-barrier scheme) ----------------
DEVFN void attn_stage_k(const unsigned short* KB, short* Ks, int kn0, int w, int l)
{
#pragma unroll
  for (int i = 0; i < 2; i++) {
    int id = (w*2 + i)*64 + l;
    int row = id >> 3, sl = id & 7;
    int sp = sl ^ (row & 7) ^ (((row >> 3) & 3) << 1);
    GL2LDS(KB + (kn0 + row)*64 + sp*8, Ks + (w*2 + i)*512);
  }
}

DEVFN void attn_stage_v(const unsigned short* VB, short* Vs, int kn0, int w, int l)
{
#pragma unroll
  for (int i = 0; i < 2; i++) {
    int id = (w*2 + i)*64 + l;
    int row = id >> 3, sl = id & 7;
    int sp = sl ^ (row & 7) ^ (((row >> 3) & 3) << 1);
    GL2LDS(VB + row*2048 + kn0 + sp*8, Vs + (w*2 + i)*512);
  }
}

DEVFN void attn_body(int abid, short* lds,
                     const unsigned short* __restrict__ Q, const unsigned short* __restrict__ Kb,
                     const unsigned short* __restrict__ VT, const unsigned* __restrict__ mp,
                     unsigned short* __restrict__ cat)
{
  int tid = threadIdx.x, w = tid >> 6, l = tid & 63;
  int c5 = l & 31, h = l >> 5;
  int hv = h*4;

  int xcd = abid & 7, slot = abid >> 3;
  int bh = xcd + ((slot >> 4) << 3);              // 0..63
  int qt = slot & 15;
  int b = bh >> 3, hd = bh & 7;
  int qw = qt*128 + w*32;

  const unsigned short* Qb = Q  + (size_t)bh*2048*64;
  const unsigned short* KB = Kb + (size_t)bh*2048*64;
  const unsigned short* VB = VT + (size_t)bh*64*2048;
  const unsigned* mrow = mp + b*2048*64 + (qw + c5)*64;

  short* K0 = lds;
  short* K1 = lds + 4096;
  short* Vb = lds + 8192;

  short8 qf[4];
#pragma unroll
  for (int dk = 0; dk < 4; dk++)
    qf[dk] = *(const short8*)&Qb[(qw + c5)*64 + dk*16 + h*8];

  // loop-invariant swizzled LDS byte-offsets
  int koff[2][4], voff[2][2][2];
#pragma unroll
  for (int kb = 0; kb < 2; kb++) {
    int row = kb*32 + c5;
    int rsw = (row & 7) ^ (((row >> 3) & 3) << 1);
#pragma unroll
    for (int dk = 0; dk < 4; dk++)
      koff[kb][dk] = (row*64 + (((dk*2 + h) ^ rsw) << 3))*2;
  }
#pragma unroll
  for (int db = 0; db < 2; db++) {
    int vrow = db*32 + c5;
    int vsw = (vrow & 7) ^ (((vrow >> 3) & 3) << 1);
#pragma unroll
    for (int kb = 0; kb < 2; kb++)
#pragma unroll
      for (int ksl = 0; ksl < 2; ksl++)
        voff[kb][ksl][db] = (vrow*64 + (((kb*4 + ksl*2 + h) ^ vsw) << 3))*2;
  }

  floatx16 oacc0, oacc1, nacc;
  const floatx16 zf16 = {0.f,0.f,0.f,0.f,0.f,0.f,0.f,0.f,0.f,0.f,0.f,0.f,0.f,0.f,0.f,0.f};
  oacc0 = zf16; oacc1 = zf16; nacc = zf16;

  const short8 ones8 = {(short)0x3F80,(short)0x3F80,(short)0x3F80,(short)0x3F80,
                        (short)0x3F80,(short)0x3F80,(short)0x3F80,(short)0x3F80}; // bf16 1.0

  // QK^T + softmax -> pk (P packed bf16)
  auto do_qkt_sm = [&](const short* Ks, uint2v wdt, unsigned (&pk)[2][4][2]) {
#pragma unroll
    for (int kb = 0; kb < 2; kb++) {
      floatx16 sacc;
      __builtin_amdgcn_s_setprio(1);
      {
        short8 kf = *(const short8*)((const char*)Ks + koff[kb][0]);
        sacc = MFMA32_BF16(kf, qf[0], zf16);
      }
#pragma unroll
      for (int dk = 1; dk < 4; dk++) {
        short8 kf = *(const short8*)((const char*)Ks + koff[kb][dk]);
        sacc = MFMA32_BF16(kf, qf[dk], sacc);
      }
      __builtin_amdgcn_s_setprio(0);

      unsigned keep = ~((kb ? wdt.y : wdt.x) >> hv);
      float ps[16];
#pragma unroll
      for (int t = 0; t < 16; t++) {
        int pos = (t >> 2)*8 + (t & 3);
        int keepm = __builtin_amdgcn_sbfe((int)keep, pos, 1);
        float p = exp2f(sacc[t]);
        ps[t] = __uint_as_float(__float_as_uint(p) & (unsigned)keepm);
      }
#pragma unroll
      for (int s = 0; s < 4; s++) {
        pk[kb][s][0] = cvtpk_bf16(ps[s*4 + 0], ps[s*4 + 1]);
        pk[kb][s][1] = cvtpk_bf16(ps[s*4 + 2], ps[s*4 + 3]);
      }
    }
  };

  auto do_pv = [&](unsigned (&pk)[2][4][2]) {
#pragma unroll
    for (int kb = 0; kb < 2; kb++) {
#pragma unroll
      for (int ksl = 0; ksl < 2; ksl++) {
        uint2v s0 = __builtin_amdgcn_permlane32_swap(pk[kb][2*ksl][0], pk[kb][2*ksl + 1][0], false, false);
        uint2v s1 = __builtin_amdgcn_permlane32_swap(pk[kb][2*ksl][1], pk[kb][2*ksl + 1][1], false, false);
        uint4v fu;
        fu[0] = s0.x; fu[1] = s1.x; fu[2] = s0.y; fu[3] = s1.y;
        short8 pfrag = *(short8*)&fu;

        __builtin_amdgcn_s_setprio(1);
        {
          short8 vf = *(const short8*)((const char*)Vb + voff[kb][ksl][0]);
          oacc0 = MFMA32_BF16(pfrag, vf, oacc0);
        }
        {
          short8 vf = *(const short8*)((const char*)Vb + voff[kb][ksl][1]);
          oacc1 = MFMA32_BF16(pfrag, vf, oacc1);
        }
        nacc = MFMA32_BF16(pfrag, ones8, nacc);
        __builtin_amdgcn_s_setprio(0);
      }
    }
  };

  // prologue: stage K(0) into K0; load mask(0)
  attn_stage_k(KB, K0, 0, w, l);
  uint2v wd = *(const uint2v*)&mrow[0];
  asm volatile("s_waitcnt vmcnt(0)" ::: "memory");
  __builtin_amdgcn_s_barrier();
  asm volatile("" ::: "memory");

  unsigned pk[2][4][2];

  for (int kt = 0; kt < 32; kt++) {
    const short* Kcur = (kt & 1) ? K1 : K0;
    short* Knext      = (kt & 1) ? K0 : K1;

    // issue this tile's V and next tile's K; both fly under QK^T+softmax
    attn_stage_v(VB, Vb, kt*64, w, l);
    uint2v wdn = wd;
    if (kt < 31) {
      attn_stage_k(KB, Knext, (kt + 1)*64, w, l);
      wdn = *(const uint2v*)&mrow[(kt + 1)*2];
    }

    do_qkt_sm(Kcur, wd, pk);

    // all waves' V (and K-next) writes landed before anyone reads Vb
    asm volatile("s_waitcnt vmcnt(0)" ::: "memory");
    __builtin_amdgcn_s_barrier();
    asm volatile("" ::: "memory");

    do_pv(pk);

    // all waves done reading Vb before next tile's stage_v overwrites it
    __builtin_amdgcn_s_barrier();
    asm volatile("" ::: "memory");

    wd = wdn;
  }

  // output: O[q = qw + (t&3)+8*(t>>2)+4h][d], col = hd*64 + db*32 + c5
#pragma unroll
  for (int t = 0; t < 16; t++) {
    float iv = 1.0f / nacc[t];
    int qrow = qw + (t & 3) + 8*(t >> 2) + hv;
    unsigned short* orow = &cat[(b*2048 + qrow)*1024 + hd*64];
    orow[c5]      = (unsigned short)f2bf(oacc0[t] * iv);
    orow[32 + c5] = (unsigned short)f2bf(oacc1[t] * iv);
  }
}

// ---------------- standalone attn (fallback path) ----------------
__global__ __launch_bounds__(256, 6)
void attn_kernel(const unsigned short* __restrict__ Q, const unsigned short* __restrict__ Kb,
                 const unsigned short* __restrict__ VT, const unsigned* __restrict__ mp,
                 unsigned short* __restrict__ cat)
{
  __shared__ short lds[12288];
  attn_body(blockIdx.x, lds, Q, Kb, VT, mp, cat);
}

// ---------------- FUSED: gemm_c (bf16 adj) + attn ----------------
__global__ __launch_bounds__(256, 6)
void fused_ca_kernel(const unsigned short* __restrict__ adjb, const unsigned short* __restrict__ xgT,
                     const unsigned short* __restrict__ Q, const unsigned short* __restrict__ Kb,
                     const unsigned short* __restrict__ VT, const unsigned* __restrict__ mp,
                     unsigned short* __restrict__ cat)
{
  __shared__ short lds[12288];
  int bid = blockIdx.x;
  int r3 = bid % 3;
  if (r3 == 2) {
    int cbid = bid / 3;
    int tid = threadIdx.x, w = tid >> 6, l = tid & 63;
    int xcd = cbid & 7, slot = cbid >> 3;
    int p  = xcd + ((slot >> 2) << 3);
    int nt = slot & 3;
    int b = p >> 4, mt = p & 15;
    int rows0 = mt*128, cols0 = nt*128;

    floatx4 acc[4][4];
    const floatx4 zf = {0.f, 0.f, 0.f, 0.f};
#pragma unroll
    for (int a2 = 0; a2 < 4; a2++)
#pragma unroll
      for (int b2 = 0; b2 < 4; b2++) acc[a2][b2] = zf;

    gemm_kloop_bf16(adjb + (size_t)b*2048*2048 + (size_t)rows0*2048, 2048,
                    xgT + (b*512 + cols0)*2048, 2048, 2048,
                    lds, lds + 4096, w, l, acc);

    int wr = (w >> 1)*64, wc = (w & 1)*64;
#pragma unroll
    for (int mi = 0; mi < 4; mi++)
#pragma unroll
      for (int bi = 0; bi < 4; bi++)
#pragma unroll
        for (int r = 0; r < 4; r++) {
          int rowg = b*2048 + rows0 + wr + mi*16 + ((l >> 4) << 2) + r;
          int col  = 512 + cols0 + wc + bi*16 + (l & 15);
          cat[rowg*1024 + col] = (unsigned short)f2bf(acc[mi][bi][r]);
        }
  } else {
    int abid = (bid / 3)*2 + r3;
    attn_body(abid, lds, Q, Kb, VT, mp, cat);
  }
}

// ---------------- GEMM-D: out = cat @ W_out + b_out (fp32 out) ----------------
__global__ __launch_bounds__(256, 2)
void gemm_d_kernel(const unsigned short* __restrict__ cat, const unsigned short* __restrict__ woutT,
                   const float* __restrict__ bout, float* __restrict__ out)
{
  __shared__ short lds[8192];
  int tid = threadIdx.x, w = tid >> 6, l = tid & 63;
  int bid = blockIdx.x;
  int xcd = bid & 7, slot = bid >> 3;
  int p  = xcd + ((slot >> 2) << 3);
  int nt = slot & 3;
  int rows0 = p*128, cols0 = nt*128;

  floatx4 acc[4][4];
  const floatx4 zf = {0.f, 0.f, 0.f, 0.f};
#pragma unroll
  for (int a2 = 0; a2 < 4; a2++)
#pragma unroll
    for (int b2 = 0; b2 < 4; b2++) acc[a2][b2] = zf;

  gemm_kloop_bf16(cat + (size_t)rows0*1024, 1024, woutT + cols0*1024, 1024, 1024,
                  lds, lds + 4096, w, l, acc);

  int wr = (w >> 1)*64, wc = (w & 1)*64;
#pragma unroll
  for (int bi = 0; bi < 4; bi++) {
    int col = cols0 + wc + bi*16 + (l & 15);
    float bias = bout[col];
#pragma unroll
    for (int mi = 0; mi < 4; mi++)
#pragma unroll
      for (int r = 0; r < 4; r++) {
        int rowg = rows0 + wr + mi*16 + ((l >> 4) << 2) + r;
        out[rowg*512 + col] = acc[mi][bi][r] + bias;
      }
  }
}

// ---------------- launch ----------------
extern "C" void kernel_launch(void* const* d_in, const int* in_sizes, int n_in,
                              void* d_out, int out_size, void* d_ws, size_t ws_size,
                              hipStream_t stream)
{
  (void)in_sizes; (void)n_in; (void)out_size;
  const float* x   = (const float*)d_in[0];
  const float* adj = (const float*)d_in[1];
  const void*  msk = d_in[2];
  const float* wg  = (const float*)d_in[3];
  const float* wq  = (const float*)d_in[4];
  const float* wo  = (const float*)d_in[5];
  const float* bo  = (const float*)d_in[6];
  float* out = (float*)d_out;
  char* ws = (char*)d_ws;

  unsigned short* xbf   = (unsigned short*)(ws + 0);          // 16,777,216
  unsigned short* wcat  = (unsigned short*)(ws + 16777216);   //  2,097,152
  unsigned short* woutT = (unsigned short*)(ws + 18874368);   //  1,048,576
  unsigned short* xgT   = (unsigned short*)(ws + 19922944);   // 16,777,216
  unsigned short* Qb    = (unsigned short*)(ws + 36700160);   // 16,777,216
  unsigned short* Kb    = (unsigned short*)(ws + 53477376);   // 16,777,216
  unsigned short* VTb   = (unsigned short*)(ws + 70254592);   // 16,777,216
  unsigned short* cat   = (unsigned short*)(ws + 87031808);   // 33,554,432
  unsigned*       mp    = (unsigned*)(ws + 120586240);        //  4,194,304
  unsigned*       flag  = (unsigned*)(ws + 124780544);        //         64
  unsigned short* adjb  = (unsigned short*)(ws + 124780608);  // 67,108,864 (optional)

  const int use_adjb = (ws_size >= (size_t)124780608 + 67108864) ? 1 : 0;

  detect_kernel<<<1, 256, 0, stream>>>((const unsigned char*)msk, flag);
  if (use_adjb) {
    prep_small_kernel<<<14336, 256, 0, stream>>>(x, wg, wq, wo, xbf, wcat, woutT);
    gemm_ab_kernel<<<22528, 256, 0, stream>>>(xbf, wcat, xgT, Qb, Kb, VTb,
                                              msk, flag, adj, mp, adjb, 1);
    fused_ca_kernel<<<1536, 256, 0, stream>>>(adjb, xgT, Qb, Kb, VTb, mp, cat);
  } else {
    prep_full_kernel<<<145408, 256, 0, stream>>>(x, wg, wq, wo, msk, flag,
                                                 xbf, wcat, woutT, mp);
    gemm_ab_kernel<<<2048, 256, 0, stream>>>(xbf, wcat, xgT, Qb, Kb, VTb,
                                             msk, flag, adj, mp, adjb, 0);
    gemm_c_f32_kernel<<<512, 256, 0, stream>>>(adj, xgT, cat);
    attn_kernel<<<1024, 256, 0, stream>>>(Qb, Kb, VTb, mp, cat);
  }
  gemm_d_kernel<<<512, 256, 0, stream>>>(cat, woutT, bo, out);
}

// Round 14
// 368.434 us; speedup vs baseline: 2.7621x; 2.7621x over previous
//
#include <hip/hip_runtime.h>
#include <stdint.h>

#define DEVFN __device__ __forceinline__

typedef __attribute__((ext_vector_type(8))) short short8;
typedef __attribute__((ext_vector_type(4))) short short4v;
typedef __attribute__((ext_vector_type(4))) float floatx4;
typedef __attribute__((ext_vector_type(16))) float floatx16;
typedef __attribute__((ext_vector_type(4))) float vfloat4;
typedef __attribute__((ext_vector_type(2))) unsigned int uint2v;
typedef __attribute__((ext_vector_type(4))) unsigned int uint4v;

#define MFMA_BF16(a,b,c) __builtin_amdgcn_mfma_f32_16x16x32_bf16((a),(b),(c),0,0,0)
#define MFMA32_BF16(a,b,c) __builtin_amdgcn_mfma_f32_32x32x16_bf16((a),(b),(c),0,0,0)
#define GL2LDS(g,l) __builtin_amdgcn_global_load_lds((const __attribute__((address_space(1))) void*)(g), (__attribute__((address_space(3))) void*)(l), 16, 0, 0)

DEVFN unsigned short f2bf(float f){
  unsigned u = __float_as_uint(f);
  u = (u + 0x7fffu + ((u >> 16) & 1u)) >> 16;
  return (unsigned short)u;
}

DEVFN unsigned cvtpk_bf16(float lo, float hi){
  unsigned r;
  asm("v_cvt_pk_bf16_f32 %0, %1, %2" : "=v"(r) : "v"(lo), "v"(hi));
  return r;
}

// ---------------- mask dtype detection ----------------
__global__ void detect_kernel(const unsigned char* m, unsigned int* flag){
  if (threadIdx.x == 0) *flag = 0u;
  __syncthreads();
  int any = 0;
  for (int i = threadIdx.x; i < 4096; i += 256)
    if ((i & 3) != 0 && m[i]) any = 1;
  if (any) atomicOr(flag, 1u);
}

// ---------------- prep (small): x->bf16, weightsT->bf16 (Q pre-scaled) ----------------
__global__ void prep_small_kernel(const float* __restrict__ x, const float* __restrict__ wg,
                                  const float* __restrict__ wq, const float* __restrict__ wo,
                                  unsigned short* __restrict__ xbf, unsigned short* __restrict__ wcat,
                                  unsigned short* __restrict__ woutT)
{
  int bid = blockIdx.x, tid = threadIdx.x;
  if (bid < 8192) {                               // x -> bf16
    int i = (bid*256 + tid)*4;
    vfloat4 v = *(const vfloat4*)&x[i];
    short4v c; c[0]=(short)f2bf(v[0]); c[1]=(short)f2bf(v[1]); c[2]=(short)f2bf(v[2]); c[3]=(short)f2bf(v[3]);
    *(short4v*)&xbf[i] = c;
  } else if (bid < 12288) {                       // WcatT (Q cols pre-scaled by 0.125*log2e)
    int i = (bid - 8192)*256 + tid;
    int k = i & 511, c = i >> 9;
    float v = (c < 512) ? wg[k*512 + c] : wq[k*1536 + (c - 512)];
    if (c >= 512 && c < 1024) v *= 0.18033688f;
    wcat[c*512 + k] = (unsigned short)f2bf(v);
  } else {                                        // WoutT
    int i = (bid - 12288)*256 + tid;
    int k = i & 1023, n2 = i >> 10;
    woutT[n2*1024 + k] = (unsigned short)f2bf(wo[k*512 + n2]);
  }
}

// ---------------- prep (full, fallback path only) ----------------
__global__ void prep_full_kernel(const float* __restrict__ x, const float* __restrict__ wg,
                                 const float* __restrict__ wq, const float* __restrict__ wo,
                                 const void* __restrict__ mask, const unsigned* __restrict__ flag,
                                 unsigned short* __restrict__ xbf, unsigned short* __restrict__ wcat,
                                 unsigned short* __restrict__ woutT, unsigned* __restrict__ mp)
{
  int bid = blockIdx.x, tid = threadIdx.x;
  if (bid < 8192) {
    int i = (bid*256 + tid)*4;
    vfloat4 v = *(const vfloat4*)&x[i];
    short4v c; c[0]=(short)f2bf(v[0]); c[1]=(short)f2bf(v[1]); c[2]=(short)f2bf(v[2]); c[3]=(short)f2bf(v[3]);
    *(short4v*)&xbf[i] = c;
  } else if (bid < 12288) {
    int i = (bid - 8192)*256 + tid;
    int k = i & 511, c = i >> 9;
    float v = (c < 512) ? wg[k*512 + c] : wq[k*1536 + (c - 512)];
    if (c >= 512 && c < 1024) v *= 0.18033688f;
    wcat[c*512 + k] = (unsigned short)f2bf(v);
  } else if (bid < 14336) {
    int i = (bid - 12288)*256 + tid;
    int k = i & 1023, n2 = i >> 10;
    woutT[n2*1024 + k] = (unsigned short)f2bf(wo[k*512 + n2]);
  } else {                                        // mask bit-pack
    int j = bid - 14336;
    int e = j*256 + tid;
    int v;
    if (*flag) v = ((const unsigned char*)mask)[e];
    else       v = ((const int*)mask)[e];
    unsigned long long ball = __ballot(v != 0);
    int base = e & ~63;
    int lane = tid & 63;
    if (lane == 0)  mp[(base >> 5) + 0] = (unsigned)(ball & 0xffffffffull);
    if (lane == 32) mp[(base >> 5) + 1] = (unsigned)(ball >> 32);
  }
}

// ---------------- shared 128x128 BK=32 bf16 K-loop (m97 structure) ----------------
DEVFN void gemm_kloop_bf16(const unsigned short* Ag, int lda,
                           const unsigned short* Bg, int ldb, int K,
                           short* As, short* Bs, int w, int l,
                           floatx4 (&acc)[4][4])
{
  const int wr = (w >> 1)*64, wc = (w & 1)*64;
  for (int k0 = 0; k0 < K; k0 += 32) {
    __syncthreads();
#pragma unroll
    for (int i = 0; i < 2; i++) {
      int id = (w*2 + i)*64 + l;
      int row = id >> 2, part = id & 3;
      GL2LDS(Ag + row*lda + k0 + part*8, As + (w*2 + i)*512);
      GL2LDS(Bg + row*ldb + k0 + part*8, Bs + (w*2 + i)*512);
    }
    __syncthreads();
    short8 af[4], bfr[4];
#pragma unroll
    for (int t = 0; t < 4; t++) {
      af[t]  = *(const short8*)&As[(wr + t*16 + (l & 15))*32 + ((l >> 4) << 3)];
      bfr[t] = *(const short8*)&Bs[(wc + t*16 + (l & 15))*32 + ((l >> 4) << 3)];
    }
#pragma unroll
    for (int a2 = 0; a2 < 4; a2++)
#pragma unroll
      for (int b2 = 0; b2 < 4; b2++)
        acc[a2][b2] = MFMA_BF16(af[a2], bfr[b2], acc[a2][b2]);
  }
}

// ---------------- GEMM-AB (+ pipelined BW blocks): xgT/Q/K/VT ; mask pack ; adj->bf16 ----------------
__global__ __launch_bounds__(256, 2)
void gemm_ab_kernel(const unsigned short* __restrict__ xbf, const unsigned short* __restrict__ wcat,
                    unsigned short* __restrict__ xgT, unsigned short* __restrict__ Qo,
                    unsigned short* __restrict__ Ko, unsigned short* __restrict__ VTo,
                    const void* __restrict__ mask, const unsigned* __restrict__ flag,
                    const float* __restrict__ adj,
                    unsigned* __restrict__ mp, unsigned short* __restrict__ adjb,
                    int mode)
{
  __shared__ short lds[16384];
  int tid = threadIdx.x, w = tid >> 6, l = tid & 63;
  int bid = blockIdx.x;

  int gemmid;
  if (mode) {
    int r11 = bid % 11, g11 = bid / 11;
    if (r11 != 0) {
      int bw = g11*10 + (r11 - 1);                // 0..20479
      if (bw < 16384) {
        unsigned fl = *flag;
        int lane = tid & 63;
        int vv[8];
        if (fl) {
          const unsigned char* m8 = (const unsigned char*)mask;
#pragma unroll
          for (int j = 0; j < 8; j++) vv[j] = m8[(bw*8 + j)*256 + tid];
        } else {
          const int* m32 = (const int*)mask;
#pragma unroll
          for (int j = 0; j < 8; j++) vv[j] = m32[(bw*8 + j)*256 + tid];
        }
#pragma unroll
        for (int j = 0; j < 8; j++) {
          unsigned long long ball = __ballot(vv[j] != 0);
          int e = (bw*8 + j)*256 + tid;
          int base = e & ~63;
          if (lane == 0)  mp[(base >> 5) + 0] = (unsigned)(ball & 0xffffffffull);
          if (lane == 32) mp[(base >> 5) + 1] = (unsigned)(ball >> 32);
        }
      } else {
        int ab = bw - 16384;
        vfloat4 vv[8];
#pragma unroll
        for (int j = 0; j < 8; j++)
          vv[j] = *(const vfloat4*)&adj[((ab*8 + j)*256 + tid)*4];
#pragma unroll
        for (int j = 0; j < 8; j++) {
          short4v c; c[0]=(short)f2bf(vv[j][0]); c[1]=(short)f2bf(vv[j][1]);
          c[2]=(short)f2bf(vv[j][2]); c[3]=(short)f2bf(vv[j][3]);
          *(short4v*)&adjb[((ab*8 + j)*256 + tid)*4] = c;
        }
      }
      return;
    }
    gemmid = g11;                                 // 0..2047
  } else {
    gemmid = bid;
  }

  int xcd = gemmid & 7, slot = gemmid >> 3;
  int p  = xcd + ((slot >> 4) << 3);
  int nt = slot & 15;
  int rows0 = p*128, cols0 = nt*128;

  floatx4 acc[4][4];
  const floatx4 zf = {0.f, 0.f, 0.f, 0.f};
#pragma unroll
  for (int a2 = 0; a2 < 4; a2++)
#pragma unroll
    for (int b2 = 0; b2 < 4; b2++) acc[a2][b2] = zf;

  gemm_kloop_bf16(xbf + rows0*512, 512, wcat + cols0*512, 512, 512,
                  lds, lds + 4096, w, l, acc);
  __syncthreads();

  int wr = (w >> 1)*64, wc = (w & 1)*64;
  int b = p >> 4;
  int n0 = (p & 15)*128 + wr;
  int gc0 = cols0 + wc;

  if (nt < 4 || nt >= 12) {
    short* T = lds + w*4096;
#pragma unroll
    for (int mi = 0; mi < 4; mi++)
#pragma unroll
      for (int bi = 0; bi < 4; bi++)
#pragma unroll
        for (int r = 0; r < 4; r++) {
          int rl = mi*16 + ((l >> 4) << 2) + r;
          int cl = bi*16 + (l & 15);
          T[cl*64 + ((((rl >> 3) ^ (cl & 7))) << 3) + (rl & 7)] = (short)f2bf(acc[mi][bi][r]);
        }
#pragma unroll
    for (int i = 0; i < 8; i++) {
      int chunk = i*64 + l;
      int c = chunk >> 3, s = chunk & 7;
      short8 v = *(const short8*)&T[c*64 + ((s ^ (c & 7)) << 3)];
      int rowstart = n0 + s*8;
      if (nt < 4) {
        int d = gc0 + c;
        *(short8*)&xgT[(b*512 + d)*2048 + rowstart] = v;
      } else {
        int vc = gc0 + c - 1536;
        int hh = vc >> 6, dd = vc & 63;
        *(short8*)&VTo[((b*8 + hh)*64 + dd)*2048 + rowstart] = v;
      }
    }
  } else {
    unsigned short* dst = (nt < 8) ? Qo : Ko;
    int cbase = gc0 - ((nt < 8) ? 512 : 1024);
    int hh = cbase >> 6;
#pragma unroll
    for (int mi = 0; mi < 4; mi++)
#pragma unroll
      for (int bi = 0; bi < 4; bi++)
#pragma unroll
        for (int r = 0; r < 4; r++) {
          int rowg = n0 + mi*16 + ((l >> 4) << 2) + r;
          int dd = bi*16 + (l & 15);
          dst[((b*8 + hh)*2048 + rowg)*64 + dd] = (unsigned short)f2bf(acc[mi][bi][r]);
        }
  }
}

// ---------------- GEMM-C (fp32 fallback, original) ----------------
__global__ __launch_bounds__(256, 2)
void gemm_c_f32_kernel(const float* __restrict__ adj, const unsigned short* __restrict__ xgT,
                       unsigned short* __restrict__ cat)
{
  __shared__ short lds[8192];
  int tid = threadIdx.x, w = tid >> 6, l = tid & 63;
  int bid = blockIdx.x;
  int xcd = bid & 7, slot = bid >> 3;
  int p  = xcd + ((slot >> 2) << 3);
  int nt = slot & 3;
  int b = p >> 4, mt = p & 15;
  int rows0 = mt*128, cols0 = nt*128;
  const float* Ag = adj + (size_t)b*2048*2048 + (size_t)rows0*2048;
  const unsigned short* Bg = xgT + (b*512 + cols0)*2048;

  floatx4 acc[4][4];
  const floatx4 zf = {0.f, 0.f, 0.f, 0.f};
#pragma unroll
  for (int a2 = 0; a2 < 4; a2++)
#pragma unroll
    for (int b2 = 0; b2 < 4; b2++) acc[a2][b2] = zf;

  const int wr = (w >> 1)*64, wc = (w & 1)*64;
  for (int k0 = 0; k0 < 2048; k0 += 32) {
    __syncthreads();
#pragma unroll
    for (int i = 0; i < 4; i++) {
      int id = (w*4 + i)*64 + l;
      int row = id >> 3, part = id & 7;
      vfloat4 v = *(const vfloat4*)&Ag[row*2048 + k0 + part*4];
      short4v c4; c4[0]=(short)f2bf(v[0]); c4[1]=(short)f2bf(v[1]); c4[2]=(short)f2bf(v[2]); c4[3]=(short)f2bf(v[3]);
      *(short4v*)&lds[row*32 + part*4] = c4;
    }
#pragma unroll
    for (int i = 0; i < 2; i++) {
      int id = (w*2 + i)*64 + l;
      int row = id >> 2, part = id & 3;
      GL2LDS(Bg + row*2048 + k0 + part*8, lds + 4096 + (w*2 + i)*512);
    }
    __syncthreads();
    short8 af[4], bfr[4];
#pragma unroll
    for (int t = 0; t < 4; t++) {
      af[t]  = *(const short8*)&lds[(wr + t*16 + (l & 15))*32 + ((l >> 4) << 3)];
      bfr[t] = *(const short8*)&lds[4096 + (wc + t*16 + (l & 15))*32 + ((l >> 4) << 3)];
    }
#pragma unroll
    for (int a2 = 0; a2 < 4; a2++)
#pragma unroll
      for (int b2 = 0; b2 < 4; b2++)
        acc[a2][b2] = MFMA_BF16(af[a2], bfr[b2], acc[a2][b2]);
  }

#pragma unroll
  for (int mi = 0; mi < 4; mi++)
#pragma unroll
    for (int bi = 0; bi < 4; bi++)
#pragma unroll
      for (int r = 0; r < 4; r++) {
        int rowg = b*2048 + rows0 + wr + mi*16 + ((l >> 4) << 2) + r;
        int col  = 512 + cols0 + wc + bi*16 + (l & 15);
        cat[rowg*1024 + col] = (unsigned short)f2bf(acc[mi][bi][r]);
      }
}

// ---------------- attn tile body (v10: K dbuf + V single-buffer, two-barrier scheme) ----------------
DEVFN void attn_stage_k(const unsigned short* KB, short* Ks, int kn0, int w, int l)
{
#pragma unroll
  for (int i = 0; i < 2; i++) {
    int id = (w*2 + i)*64 + l;
    int row = id >> 3, sl = id & 7;
    int sp = sl ^ (row & 7) ^ (((row >> 3) & 3) << 1);
    GL2LDS(KB + (kn0 + row)*64 + sp*8, Ks + (w*2 + i)*512);
  }
}

DEVFN void attn_stage_v(const unsigned short* VB, short* Vs, int kn0, int w, int l)
{
#pragma unroll
  for (int i = 0; i < 2; i++) {
    int id = (w*2 + i)*64 + l;
    int row = id >> 3, sl = id & 7;
    int sp = sl ^ (row & 7) ^ (((row >> 3) & 3) << 1);
    GL2LDS(VB + row*2048 + kn0 + sp*8, Vs + (w*2 + i)*512);
  }
}

DEVFN void attn_body(int abid, short* lds,
                     const unsigned short* __restrict__ Q, const unsigned short* __restrict__ Kb,
                     const unsigned short* __restrict__ VT, const unsigned* __restrict__ mp,
                     unsigned short* __restrict__ cat)
{
  int tid = threadIdx.x, w = tid >> 6, l = tid & 63;
  int c5 = l & 31, h = l >> 5;
  int hv = h*4;

  int xcd = abid & 7, slot = abid >> 3;
  int bh = xcd + ((slot >> 4) << 3);              // 0..63
  int qt = slot & 15;
  int b = bh >> 3, hd = bh & 7;
  int qw = qt*128 + w*32;

  const unsigned short* Qb = Q  + (size_t)bh*2048*64;
  const unsigned short* KB = Kb + (size_t)bh*2048*64;
  const unsigned short* VB = VT + (size_t)bh*64*2048;
  const unsigned* mrow = mp + b*2048*64 + (qw + c5)*64;

  short* K0 = lds;
  short* K1 = lds + 4096;
  short* Vb = lds + 8192;

  short8 qf[4];
#pragma unroll
  for (int dk = 0; dk < 4; dk++)
    qf[dk] = *(const short8*)&Qb[(qw + c5)*64 + dk*16 + h*8];

  // loop-invariant swizzled LDS byte-offsets
  int koff[2][4], voff[2][2][2];
#pragma unroll
  for (int kb = 0; kb < 2; kb++) {
    int row = kb*32 + c5;
    int rsw = (row & 7) ^ (((row >> 3) & 3) << 1);
#pragma unroll
    for (int dk = 0; dk < 4; dk++)
      koff[kb][dk] = (row*64 + (((dk*2 + h) ^ rsw) << 3))*2;
  }
#pragma unroll
  for (int db = 0; db < 2; db++) {
    int vrow = db*32 + c5;
    int vsw = (vrow & 7) ^ (((vrow >> 3) & 3) << 1);
#pragma unroll
    for (int kb = 0; kb < 2; kb++)
#pragma unroll
      for (int ksl = 0; ksl < 2; ksl++)
        voff[kb][ksl][db] = (vrow*64 + (((kb*4 + ksl*2 + h) ^ vsw) << 3))*2;
  }

  floatx16 oacc0, oacc1, nacc;
  const floatx16 zf16 = {0.f,0.f,0.f,0.f,0.f,0.f,0.f,0.f,0.f,0.f,0.f,0.f,0.f,0.f,0.f,0.f};
  oacc0 = zf16; oacc1 = zf16; nacc = zf16;

  const short8 ones8 = {(short)0x3F80,(short)0x3F80,(short)0x3F80,(short)0x3F80,
                        (short)0x3F80,(short)0x3F80,(short)0x3F80,(short)0x3F80}; // bf16 1.0

  // QK^T + softmax -> pk (P packed bf16)
  auto do_qkt_sm = [&](const short* Ks, uint2v wdt, unsigned (&pk)[2][4][2]) {
#pragma unroll
    for (int kb = 0; kb < 2; kb++) {
      floatx16 sacc;
      __builtin_amdgcn_s_setprio(1);
      {
        short8 kf = *(const short8*)((const char*)Ks + koff[kb][0]);
        sacc = MFMA32_BF16(kf, qf[0], zf16);
      }
#pragma unroll
      for (int dk = 1; dk < 4; dk++) {
        short8 kf = *(const short8*)((const char*)Ks + koff[kb][dk]);
        sacc = MFMA32_BF16(kf, qf[dk], sacc);
      }
      __builtin_amdgcn_s_setprio(0);

      unsigned keep = ~((kb ? wdt.y : wdt.x) >> hv);
      float ps[16];
#pragma unroll
      for (int t = 0; t < 16; t++) {
        int pos = (t >> 2)*8 + (t & 3);
        int keepm = __builtin_amdgcn_sbfe((int)keep, pos, 1);
        float p = exp2f(sacc[t]);
        ps[t] = __uint_as_float(__float_as_uint(p) & (unsigned)keepm);
      }
#pragma unroll
      for (int s = 0; s < 4; s++) {
        pk[kb][s][0] = cvtpk_bf16(ps[s*4 + 0], ps[s*4 + 1]);
        pk[kb][s][1] = cvtpk_bf16(ps[s*4 + 2], ps[s*4 + 3]);
      }
    }
  };

  auto do_pv = [&](unsigned (&pk)[2][4][2]) {
#pragma unroll
    for (int kb = 0; kb < 2; kb++) {
#pragma unroll
      for (int ksl = 0; ksl < 2; ksl++) {
        uint2v s0 = __builtin_amdgcn_permlane32_swap(pk[kb][2*ksl][0], pk[kb][2*ksl + 1][0], false, false);
        uint2v s1 = __builtin_amdgcn_permlane32_swap(pk[kb][2*ksl][1], pk[kb][2*ksl + 1][1], false, false);
        uint4v fu;
        fu[0] = s0.x; fu[1] = s1.x; fu[2] = s0.y; fu[3] = s1.y;
        short8 pfrag = *(short8*)&fu;

        __builtin_amdgcn_s_setprio(1);
        {
          short8 vf = *(const short8*)((const char*)Vb + voff[kb][ksl][0]);
          oacc0 = MFMA32_BF16(pfrag, vf, oacc0);
        }
        {
          short8 vf = *(const short8*)((const char*)Vb + voff[kb][ksl][1]);
          oacc1 = MFMA32_BF16(pfrag, vf, oacc1);
        }
        nacc = MFMA32_BF16(pfrag, ones8, nacc);
        __builtin_amdgcn_s_setprio(0);
      }
    }
  };

  // prologue: stage K(0) into K0; load mask(0)
  attn_stage_k(KB, K0, 0, w, l);
  uint2v wd = *(const uint2v*)&mrow[0];
  asm volatile("s_waitcnt vmcnt(0)" ::: "memory");
  __builtin_amdgcn_s_barrier();
  asm volatile("" ::: "memory");

  unsigned pk[2][4][2];

  for (int kt = 0; kt < 32; kt++) {
    const short* Kcur = (kt & 1) ? K1 : K0;
    short* Knext      = (kt & 1) ? K0 : K1;

    // issue this tile's V and next tile's K; both fly under QK^T+softmax
    attn_stage_v(VB, Vb, kt*64, w, l);
    uint2v wdn = wd;
    if (kt < 31) {
      attn_stage_k(KB, Knext, (kt + 1)*64, w, l);
      wdn = *(const uint2v*)&mrow[(kt + 1)*2];
    }

    do_qkt_sm(Kcur, wd, pk);

    // all waves' V (and K-next) writes landed before anyone reads Vb
    asm volatile("s_waitcnt vmcnt(0)" ::: "memory");
    __builtin_amdgcn_s_barrier();
    asm volatile("" ::: "memory");

    do_pv(pk);

    // all waves done reading Vb before next tile's stage_v overwrites it
    __builtin_amdgcn_s_barrier();
    asm volatile("" ::: "memory");

    wd = wdn;
  }

  // output: O[q = qw + (t&3)+8*(t>>2)+4h][d], col = hd*64 + db*32 + c5
#pragma unroll
  for (int t = 0; t < 16; t++) {
    float iv = 1.0f / nacc[t];
    int qrow = qw + (t & 3) + 8*(t >> 2) + hv;
    unsigned short* orow = &cat[(b*2048 + qrow)*1024 + hd*64];
    orow[c5]      = (unsigned short)f2bf(oacc0[t] * iv);
    orow[32 + c5] = (unsigned short)f2bf(oacc1[t] * iv);
  }
}

// ---------------- standalone attn (fallback path) ----------------
__global__ __launch_bounds__(256, 4)
void attn_kernel(const unsigned short* __restrict__ Q, const unsigned short* __restrict__ Kb,
                 const unsigned short* __restrict__ VT, const unsigned* __restrict__ mp,
                 unsigned short* __restrict__ cat)
{
  __shared__ short lds[12288];
  attn_body(blockIdx.x, lds, Q, Kb, VT, mp, cat);
}

// ---------------- FUSED: gemm_c (bf16 adj) + attn ----------------
__global__ __launch_bounds__(256, 4)
void fused_ca_kernel(const unsigned short* __restrict__ adjb, const unsigned short* __restrict__ xgT,
                     const unsigned short* __restrict__ Q, const unsigned short* __restrict__ Kb,
                     const unsigned short* __restrict__ VT, const unsigned* __restrict__ mp,
                     unsigned short* __restrict__ cat)
{
  __shared__ short lds[12288];
  int bid = blockIdx.x;
  int r3 = bid % 3;
  if (r3 == 2) {
    int cbid = bid / 3;
    int tid = threadIdx.x, w = tid >> 6, l = tid & 63;
    int xcd = cbid & 7, slot = cbid >> 3;
    int p  = xcd + ((slot >> 2) << 3);
    int nt = slot & 3;
    int b = p >> 4, mt = p & 15;
    int rows0 = mt*128, cols0 = nt*128;

    floatx4 acc[4][4];
    const floatx4 zf = {0.f, 0.f, 0.f, 0.f};
#pragma unroll
    for (int a2 = 0; a2 < 4; a2++)
#pragma unroll
      for (int b2 = 0; b2 < 4; b2++) acc[a2][b2] = zf;

    gemm_kloop_bf16(adjb + (size_t)b*2048*2048 + (size_t)rows0*2048, 2048,
                    xgT + (b*512 + cols0)*2048, 2048, 2048,
                    lds, lds + 4096, w, l, acc);

    int wr = (w >> 1)*64, wc = (w & 1)*64;
#pragma unroll
    for (int mi = 0; mi < 4; mi++)
#pragma unroll
      for (int bi = 0; bi < 4; bi++)
#pragma unroll
        for (int r = 0; r < 4; r++) {
          int rowg = b*2048 + rows0 + wr + mi*16 + ((l >> 4) << 2) + r;
          int col  = 512 + cols0 + wc + bi*16 + (l & 15);
          cat[rowg*1024 + col] = (unsigned short)f2bf(acc[mi][bi][r]);
        }
  } else {
    int abid = (bid / 3)*2 + r3;
    attn_body(abid, lds, Q, Kb, VT, mp, cat);
  }
}

// ---------------- GEMM-D: out = cat @ W_out + b_out (fp32 out) ----------------
__global__ __launch_bounds__(256, 2)
void gemm_d_kernel(const unsigned short* __restrict__ cat, const unsigned short* __restrict__ woutT,
                   const float* __restrict__ bout, float* __restrict__ out)
{
  __shared__ short lds[8192];
  int tid = threadIdx.x, w = tid >> 6, l = tid & 63;
  int bid = blockIdx.x;
  int xcd = bid & 7, slot = bid >> 3;
  int p  = xcd + ((slot >> 2) << 3);
  int nt = slot & 3;
  int rows0 = p*128, cols0 = nt*128;

  floatx4 acc[4][4];
  const floatx4 zf = {0.f, 0.f, 0.f, 0.f};
#pragma unroll
  for (int a2 = 0; a2 < 4; a2++)
#pragma unroll
    for (int b2 = 0; b2 < 4; b2++) acc[a2][b2] = zf;

  gemm_kloop_bf16(cat + (size_t)rows0*1024, 1024, woutT + cols0*1024, 1024, 1024,
                  lds, lds + 4096, w, l, acc);

  int wr = (w >> 1)*64, wc = (w & 1)*64;
#pragma unroll
  for (int bi = 0; bi < 4; bi++) {
    int col = cols0 + wc + bi*16 + (l & 15);
    float bias = bout[col];
#pragma unroll
    for (int mi = 0; mi < 4; mi++)
#pragma unroll
      for (int r = 0; r < 4; r++) {
        int rowg = rows0 + wr + mi*16 + ((l >> 4) << 2) + r;
        out[rowg*512 + col] = acc[mi][bi][r] + bias;
      }
  }
}

// ---------------- launch ----------------
extern "C" void kernel_launch(void* const* d_in, const int* in_sizes, int n_in,
                              void* d_out, int out_size, void* d_ws, size_t ws_size,
                              hipStream_t stream)
{
  (void)in_sizes; (void)n_in; (void)out_size;
  const float* x   = (const float*)d_in[0];
  const float* adj = (const float*)d_in[1];
  const void*  msk = d_in[2];
  const float* wg  = (const float*)d_in[3];
  const float* wq  = (const float*)d_in[4];
  const float* wo  = (const float*)d_in[5];
  const float* bo  = (const float*)d_in[6];
  float* out = (float*)d_out;
  char* ws = (char*)d_ws;

  unsigned short* xbf   = (unsigned short*)(ws + 0);          // 16,777,216
  unsigned short* wcat  = (unsigned short*)(ws + 16777216);   //  2,097,152
  unsigned short* woutT = (unsigned short*)(ws + 18874368);   //  1,048,576
  unsigned short* xgT   = (unsigned short*)(ws + 19922944);   // 16,777,216
  unsigned short* Qb    = (unsigned short*)(ws + 36700160);   // 16,777,216
  unsigned short* Kb    = (unsigned short*)(ws + 53477376);   // 16,777,216
  unsigned short* VTb   = (unsigned short*)(ws + 70254592);   // 16,777,216
  unsigned short* cat   = (unsigned short*)(ws + 87031808);   // 33,554,432
  unsigned*       mp    = (unsigned*)(ws + 120586240);        //  4,194,304
  unsigned*       flag  = (unsigned*)(ws + 124780544);        //         64
  unsigned short* adjb  = (unsigned short*)(ws + 124780608);  // 67,108,864 (optional)

  const int use_adjb = (ws_size >= (size_t)124780608 + 67108864) ? 1 : 0;

  detect_kernel<<<1, 256, 0, stream>>>((const unsigned char*)msk, flag);
  if (use_adjb) {
    prep_small_kernel<<<14336, 256, 0, stream>>>(x, wg, wq, wo, xbf, wcat, woutT);
    gemm_ab_kernel<<<22528, 256, 0, stream>>>(xbf, wcat, xgT, Qb, Kb, VTb,
                                              msk, flag, adj, mp, adjb, 1);
    fused_ca_kernel<<<1536, 256, 0, stream>>>(adjb, xgT, Qb, Kb, VTb, mp, cat);
  } else {
    prep_full_kernel<<<145408, 256, 0, stream>>>(x, wg, wq, wo, msk, flag,
                                                 xbf, wcat, woutT, mp);
    gemm_ab_kernel<<<2048, 256, 0, stream>>>(xbf, wcat, xgT, Qb, Kb, VTb,
                                             msk, flag, adj, mp, adjb, 0);
    gemm_c_f32_kernel<<<512, 256, 0, stream>>>(adj, xgT, cat);
    attn_kernel<<<1024, 256, 0, stream>>>(Qb, Kb, VTb, mp, cat);
  }
  gemm_d_kernel<<<512, 256, 0, stream>>>(cat, woutT, bo, out);
}

// Round 15
// 363.175 us; speedup vs baseline: 2.8021x; 1.0145x over previous
//
#include <hip/hip_runtime.h>
#include <stdint.h>

#define DEVFN __device__ __forceinline__

typedef __attribute__((ext_vector_type(8))) short short8;
typedef __attribute__((ext_vector_type(4))) short short4v;
typedef __attribute__((ext_vector_type(4))) float floatx4;
typedef __attribute__((ext_vector_type(16))) float floatx16;
typedef __attribute__((ext_vector_type(4))) float vfloat4;
typedef __attribute__((ext_vector_type(2))) unsigned int uint2v;
typedef __attribute__((ext_vector_type(4))) unsigned int uint4v;

#define MFMA_BF16(a,b,c) __builtin_amdgcn_mfma_f32_16x16x32_bf16((a),(b),(c),0,0,0)
#define MFMA32_BF16(a,b,c) __builtin_amdgcn_mfma_f32_32x32x16_bf16((a),(b),(c),0,0,0)
#define GL2LDS(g,l) __builtin_amdgcn_global_load_lds((const __attribute__((address_space(1))) void*)(g), (__attribute__((address_space(3))) void*)(l), 16, 0, 0)

DEVFN unsigned short f2bf(float f){
  unsigned u = __float_as_uint(f);
  u = (u + 0x7fffu + ((u >> 16) & 1u)) >> 16;
  return (unsigned short)u;
}

DEVFN unsigned cvtpk_bf16(float lo, float hi){
  unsigned r;
  asm("v_cvt_pk_bf16_f32 %0, %1, %2" : "=v"(r) : "v"(lo), "v"(hi));
  return r;
}

// ---------------- mask dtype detection ----------------
__global__ void detect_kernel(const unsigned char* m, unsigned int* flag){
  if (threadIdx.x == 0) *flag = 0u;
  __syncthreads();
  int any = 0;
  for (int i = threadIdx.x; i < 4096; i += 256)
    if ((i & 3) != 0 && m[i]) any = 1;
  if (any) atomicOr(flag, 1u);
}

// ---------------- prep (small): x->bf16, weightsT->bf16 (Q pre-scaled) ----------------
__global__ void prep_small_kernel(const float* __restrict__ x, const float* __restrict__ wg,
                                  const float* __restrict__ wq, const float* __restrict__ wo,
                                  unsigned short* __restrict__ xbf, unsigned short* __restrict__ wcat,
                                  unsigned short* __restrict__ woutT)
{
  int bid = blockIdx.x, tid = threadIdx.x;
  if (bid < 8192) {                               // x -> bf16
    int i = (bid*256 + tid)*4;
    vfloat4 v = *(const vfloat4*)&x[i];
    short4v c; c[0]=(short)f2bf(v[0]); c[1]=(short)f2bf(v[1]); c[2]=(short)f2bf(v[2]); c[3]=(short)f2bf(v[3]);
    *(short4v*)&xbf[i] = c;
  } else if (bid < 12288) {                       // WcatT (Q cols pre-scaled by 0.125*log2e)
    int i = (bid - 8192)*256 + tid;
    int k = i & 511, c = i >> 9;
    float v = (c < 512) ? wg[k*512 + c] : wq[k*1536 + (c - 512)];
    if (c >= 512 && c < 1024) v *= 0.18033688f;
    wcat[c*512 + k] = (unsigned short)f2bf(v);
  } else {                                        // WoutT
    int i = (bid - 12288)*256 + tid;
    int k = i & 1023, n2 = i >> 10;
    woutT[n2*1024 + k] = (unsigned short)f2bf(wo[k*512 + n2]);
  }
}

// ---------------- prep (full, fallback path only) ----------------
__global__ void prep_full_kernel(const float* __restrict__ x, const float* __restrict__ wg,
                                 const float* __restrict__ wq, const float* __restrict__ wo,
                                 const void* __restrict__ mask, const unsigned* __restrict__ flag,
                                 unsigned short* __restrict__ xbf, unsigned short* __restrict__ wcat,
                                 unsigned short* __restrict__ woutT, unsigned* __restrict__ mp)
{
  int bid = blockIdx.x, tid = threadIdx.x;
  if (bid < 8192) {
    int i = (bid*256 + tid)*4;
    vfloat4 v = *(const vfloat4*)&x[i];
    short4v c; c[0]=(short)f2bf(v[0]); c[1]=(short)f2bf(v[1]); c[2]=(short)f2bf(v[2]); c[3]=(short)f2bf(v[3]);
    *(short4v*)&xbf[i] = c;
  } else if (bid < 12288) {
    int i = (bid - 8192)*256 + tid;
    int k = i & 511, c = i >> 9;
    float v = (c < 512) ? wg[k*512 + c] : wq[k*1536 + (c - 512)];
    if (c >= 512 && c < 1024) v *= 0.18033688f;
    wcat[c*512 + k] = (unsigned short)f2bf(v);
  } else if (bid < 14336) {
    int i = (bid - 12288)*256 + tid;
    int k = i & 1023, n2 = i >> 10;
    woutT[n2*1024 + k] = (unsigned short)f2bf(wo[k*512 + n2]);
  } else {                                        // mask bit-pack
    int j = bid - 14336;
    int e = j*256 + tid;
    int v;
    if (*flag) v = ((const unsigned char*)mask)[e];
    else       v = ((const int*)mask)[e];
    unsigned long long ball = __ballot(v != 0);
    int base = e & ~63;
    int lane = tid & 63;
    if (lane == 0)  mp[(base >> 5) + 0] = (unsigned)(ball & 0xffffffffull);
    if (lane == 32) mp[(base >> 5) + 1] = (unsigned)(ball >> 32);
  }
}

// ---------------- shared 128x128 BK=32 bf16 K-loop (m97 structure) ----------------
DEVFN void gemm_kloop_bf16(const unsigned short* Ag, int lda,
                           const unsigned short* Bg, int ldb, int K,
                           short* As, short* Bs, int w, int l,
                           floatx4 (&acc)[4][4])
{
  const int wr = (w >> 1)*64, wc = (w & 1)*64;
  for (int k0 = 0; k0 < K; k0 += 32) {
    __syncthreads();
#pragma unroll
    for (int i = 0; i < 2; i++) {
      int id = (w*2 + i)*64 + l;
      int row = id >> 2, part = id & 3;
      GL2LDS(Ag + row*lda + k0 + part*8, As + (w*2 + i)*512);
      GL2LDS(Bg + row*ldb + k0 + part*8, Bs + (w*2 + i)*512);
    }
    __syncthreads();
    short8 af[4], bfr[4];
#pragma unroll
    for (int t = 0; t < 4; t++) {
      af[t]  = *(const short8*)&As[(wr + t*16 + (l & 15))*32 + ((l >> 4) << 3)];
      bfr[t] = *(const short8*)&Bs[(wc + t*16 + (l & 15))*32 + ((l >> 4) << 3)];
    }
#pragma unroll
    for (int a2 = 0; a2 < 4; a2++)
#pragma unroll
      for (int b2 = 0; b2 < 4; b2++)
        acc[a2][b2] = MFMA_BF16(af[a2], bfr[b2], acc[a2][b2]);
  }
}

// ---------------- GEMM-AB (+ pipelined BW blocks): xgT/Q/K/VT ; mask pack ; adj->bf16 ----------------
__global__ __launch_bounds__(256, 2)
void gemm_ab_kernel(const unsigned short* __restrict__ xbf, const unsigned short* __restrict__ wcat,
                    unsigned short* __restrict__ xgT, unsigned short* __restrict__ Qo,
                    unsigned short* __restrict__ Ko, unsigned short* __restrict__ VTo,
                    const void* __restrict__ mask, const unsigned* __restrict__ flag,
                    const float* __restrict__ adj,
                    unsigned* __restrict__ mp, unsigned short* __restrict__ adjb,
                    int mode)
{
  __shared__ short lds[16384];
  int tid = threadIdx.x, w = tid >> 6, l = tid & 63;
  int bid = blockIdx.x;

  int gemmid;
  if (mode) {
    int r11 = bid % 11, g11 = bid / 11;
    if (r11 != 0) {
      int bw = g11*10 + (r11 - 1);                // 0..20479
      if (bw < 16384) {
        unsigned fl = *flag;
        int lane = tid & 63;
        int vv[8];
        if (fl) {
          const unsigned char* m8 = (const unsigned char*)mask;
#pragma unroll
          for (int j = 0; j < 8; j++) vv[j] = m8[(bw*8 + j)*256 + tid];
        } else {
          const int* m32 = (const int*)mask;
#pragma unroll
          for (int j = 0; j < 8; j++) vv[j] = m32[(bw*8 + j)*256 + tid];
        }
#pragma unroll
        for (int j = 0; j < 8; j++) {
          unsigned long long ball = __ballot(vv[j] != 0);
          int e = (bw*8 + j)*256 + tid;
          int base = e & ~63;
          if (lane == 0)  mp[(base >> 5) + 0] = (unsigned)(ball & 0xffffffffull);
          if (lane == 32) mp[(base >> 5) + 1] = (unsigned)(ball >> 32);
        }
      } else {
        int ab = bw - 16384;
        vfloat4 vv[8];
#pragma unroll
        for (int j = 0; j < 8; j++)
          vv[j] = *(const vfloat4*)&adj[((ab*8 + j)*256 + tid)*4];
#pragma unroll
        for (int j = 0; j < 8; j++) {
          short4v c; c[0]=(short)f2bf(vv[j][0]); c[1]=(short)f2bf(vv[j][1]);
          c[2]=(short)f2bf(vv[j][2]); c[3]=(short)f2bf(vv[j][3]);
          *(short4v*)&adjb[((ab*8 + j)*256 + tid)*4] = c;
        }
      }
      return;
    }
    gemmid = g11;                                 // 0..2047
  } else {
    gemmid = bid;
  }

  int xcd = gemmid & 7, slot = gemmid >> 3;
  int p  = xcd + ((slot >> 4) << 3);
  int nt = slot & 15;
  int rows0 = p*128, cols0 = nt*128;

  floatx4 acc[4][4];
  const floatx4 zf = {0.f, 0.f, 0.f, 0.f};
#pragma unroll
  for (int a2 = 0; a2 < 4; a2++)
#pragma unroll
    for (int b2 = 0; b2 < 4; b2++) acc[a2][b2] = zf;

  gemm_kloop_bf16(xbf + rows0*512, 512, wcat + cols0*512, 512, 512,
                  lds, lds + 4096, w, l, acc);
  __syncthreads();

  int wr = (w >> 1)*64, wc = (w & 1)*64;
  int b = p >> 4;
  int n0 = (p & 15)*128 + wr;
  int gc0 = cols0 + wc;

  if (nt < 4 || nt >= 12) {
    short* T = lds + w*4096;
#pragma unroll
    for (int mi = 0; mi < 4; mi++)
#pragma unroll
      for (int bi = 0; bi < 4; bi++)
#pragma unroll
        for (int r = 0; r < 4; r++) {
          int rl = mi*16 + ((l >> 4) << 2) + r;
          int cl = bi*16 + (l & 15);
          T[cl*64 + ((((rl >> 3) ^ (cl & 7))) << 3) + (rl & 7)] = (short)f2bf(acc[mi][bi][r]);
        }
#pragma unroll
    for (int i = 0; i < 8; i++) {
      int chunk = i*64 + l;
      int c = chunk >> 3, s = chunk & 7;
      short8 v = *(const short8*)&T[c*64 + ((s ^ (c & 7)) << 3)];
      int rowstart = n0 + s*8;
      if (nt < 4) {
        int d = gc0 + c;
        *(short8*)&xgT[(b*512 + d)*2048 + rowstart] = v;
      } else {
        int vc = gc0 + c - 1536;
        int hh = vc >> 6, dd = vc & 63;
        *(short8*)&VTo[((b*8 + hh)*64 + dd)*2048 + rowstart] = v;
      }
    }
  } else {
    unsigned short* dst = (nt < 8) ? Qo : Ko;
    int cbase = gc0 - ((nt < 8) ? 512 : 1024);
    int hh = cbase >> 6;
#pragma unroll
    for (int mi = 0; mi < 4; mi++)
#pragma unroll
      for (int bi = 0; bi < 4; bi++)
#pragma unroll
        for (int r = 0; r < 4; r++) {
          int rowg = n0 + mi*16 + ((l >> 4) << 2) + r;
          int dd = bi*16 + (l & 15);
          dst[((b*8 + hh)*2048 + rowg)*64 + dd] = (unsigned short)f2bf(acc[mi][bi][r]);
        }
  }
}

// ---------------- GEMM-C (fp32 fallback, original) ----------------
__global__ __launch_bounds__(256, 2)
void gemm_c_f32_kernel(const float* __restrict__ adj, const unsigned short* __restrict__ xgT,
                       unsigned short* __restrict__ cat)
{
  __shared__ short lds[8192];
  int tid = threadIdx.x, w = tid >> 6, l = tid & 63;
  int bid = blockIdx.x;
  int xcd = bid & 7, slot = bid >> 3;
  int p  = xcd + ((slot >> 2) << 3);
  int nt = slot & 3;
  int b = p >> 4, mt = p & 15;
  int rows0 = mt*128, cols0 = nt*128;
  const float* Ag = adj + (size_t)b*2048*2048 + (size_t)rows0*2048;
  const unsigned short* Bg = xgT + (b*512 + cols0)*2048;

  floatx4 acc[4][4];
  const floatx4 zf = {0.f, 0.f, 0.f, 0.f};
#pragma unroll
  for (int a2 = 0; a2 < 4; a2++)
#pragma unroll
    for (int b2 = 0; b2 < 4; b2++) acc[a2][b2] = zf;

  const int wr = (w >> 1)*64, wc = (w & 1)*64;
  for (int k0 = 0; k0 < 2048; k0 += 32) {
    __syncthreads();
#pragma unroll
    for (int i = 0; i < 4; i++) {
      int id = (w*4 + i)*64 + l;
      int row = id >> 3, part = id & 7;
      vfloat4 v = *(const vfloat4*)&Ag[row*2048 + k0 + part*4];
      short4v c4; c4[0]=(short)f2bf(v[0]); c4[1]=(short)f2bf(v[1]); c4[2]=(short)f2bf(v[2]); c4[3]=(short)f2bf(v[3]);
      *(short4v*)&lds[row*32 + part*4] = c4;
    }
#pragma unroll
    for (int i = 0; i < 2; i++) {
      int id = (w*2 + i)*64 + l;
      int row = id >> 2, part = id & 3;
      GL2LDS(Bg + row*2048 + k0 + part*8, lds + 4096 + (w*2 + i)*512);
    }
    __syncthreads();
    short8 af[4], bfr[4];
#pragma unroll
    for (int t = 0; t < 4; t++) {
      af[t]  = *(const short8*)&lds[(wr + t*16 + (l & 15))*32 + ((l >> 4) << 3)];
      bfr[t] = *(const short8*)&lds[4096 + (wc + t*16 + (l & 15))*32 + ((l >> 4) << 3)];
    }
#pragma unroll
    for (int a2 = 0; a2 < 4; a2++)
#pragma unroll
      for (int b2 = 0; b2 < 4; b2++)
        acc[a2][b2] = MFMA_BF16(af[a2], bfr[b2], acc[a2][b2]);
  }

#pragma unroll
  for (int mi = 0; mi < 4; mi++)
#pragma unroll
    for (int bi = 0; bi < 4; bi++)
#pragma unroll
      for (int r = 0; r < 4; r++) {
        int rowg = b*2048 + rows0 + wr + mi*16 + ((l >> 4) << 2) + r;
        int col  = 512 + cols0 + wc + bi*16 + (l & 15);
        cat[rowg*1024 + col] = (unsigned short)f2bf(acc[mi][bi][r]);
      }
}

// ---------------- attn tile body (v8: static LDS offsets, kt unrolled x2) ----------------
DEVFN void attn_stage(const unsigned short* KB, const unsigned short* VB,
                      short* Ks, short* Vs, int kn0, int w, int l)
{
#pragma unroll
  for (int i = 0; i < 2; i++) {
    int id = (w*2 + i)*64 + l;
    int row = id >> 3, sl = id & 7;
    int sp = sl ^ (row & 7) ^ (((row >> 3) & 3) << 1);
    GL2LDS(KB + (kn0 + row)*64 + sp*8, Ks + (w*2 + i)*512);
    GL2LDS(VB + row*2048 + kn0 + sp*8, Vs + (w*2 + i)*512);
  }
}

DEVFN void attn_body(int abid, short* lds,
                     const unsigned short* __restrict__ Q, const unsigned short* __restrict__ Kb,
                     const unsigned short* __restrict__ VT, const unsigned* __restrict__ mp,
                     unsigned short* __restrict__ cat)
{
  int tid = threadIdx.x, w = tid >> 6, l = tid & 63;
  int c5 = l & 31, h = l >> 5;
  int hv = h*4;

  int xcd = abid & 7, slot = abid >> 3;
  int bh = xcd + ((slot >> 4) << 3);              // 0..63
  int qt = slot & 15;
  int b = bh >> 3, hd = bh & 7;
  int qw = qt*128 + w*32;

  const unsigned short* Qb = Q  + (size_t)bh*2048*64;
  const unsigned short* KB = Kb + (size_t)bh*2048*64;
  const unsigned short* VB = VT + (size_t)bh*64*2048;
  const unsigned* mrow = mp + b*2048*64 + (qw + c5)*64;

  short8 qf[4];
#pragma unroll
  for (int dk = 0; dk < 4; dk++)
    qf[dk] = *(const short8*)&Qb[(qw + c5)*64 + dk*16 + h*8];

  // loop-invariant swizzled LDS byte-offsets (static after unroll)
  int koff[2][4], voff[2][2][2];
#pragma unroll
  for (int kb = 0; kb < 2; kb++) {
    int row = kb*32 + c5;
    int rsw = (row & 7) ^ (((row >> 3) & 3) << 1);
#pragma unroll
    for (int dk = 0; dk < 4; dk++)
      koff[kb][dk] = (row*64 + (((dk*2 + h) ^ rsw) << 3))*2;
  }
#pragma unroll
  for (int db = 0; db < 2; db++) {
    int vrow = db*32 + c5;
    int vsw = (vrow & 7) ^ (((vrow >> 3) & 3) << 1);
#pragma unroll
    for (int kb = 0; kb < 2; kb++)
#pragma unroll
      for (int ksl = 0; ksl < 2; ksl++)
        voff[kb][ksl][db] = (vrow*64 + (((kb*4 + ksl*2 + h) ^ vsw) << 3))*2;
  }

  floatx16 oacc0, oacc1, nacc;
  const floatx16 zf16 = {0.f,0.f,0.f,0.f,0.f,0.f,0.f,0.f,0.f,0.f,0.f,0.f,0.f,0.f,0.f,0.f};
  oacc0 = zf16; oacc1 = zf16; nacc = zf16;

  const short8 ones8 = {(short)0x3F80,(short)0x3F80,(short)0x3F80,(short)0x3F80,
                        (short)0x3F80,(short)0x3F80,(short)0x3F80,(short)0x3F80}; // bf16 1.0

  auto do_tile = [&](const short* Ks, const short* Vs, uint2v wdt) {
#pragma unroll
    for (int kb = 0; kb < 2; kb++) {
      floatx16 sacc;
      __builtin_amdgcn_s_setprio(1);
      {
        short8 kf = *(const short8*)((const char*)Ks + koff[kb][0]);
        sacc = MFMA32_BF16(kf, qf[0], zf16);      // fused zero-init
      }
#pragma unroll
      for (int dk = 1; dk < 4; dk++) {
        short8 kf = *(const short8*)((const char*)Ks + koff[kb][dk]);
        sacc = MFMA32_BF16(kf, qf[dk], sacc);
      }
      __builtin_amdgcn_s_setprio(0);

      unsigned keep = ~((kb ? wdt.y : wdt.x) >> hv);
      float ps[16];
#pragma unroll
      for (int t = 0; t < 16; t++) {
        int pos = (t >> 2)*8 + (t & 3);
        int keepm = __builtin_amdgcn_sbfe((int)keep, pos, 1);  // -1 keep, 0 masked
        float p = exp2f(sacc[t]);
        ps[t] = __uint_as_float(__float_as_uint(p) & (unsigned)keepm);
      }
      unsigned pk[4][2];
#pragma unroll
      for (int s = 0; s < 4; s++) {
        pk[s][0] = cvtpk_bf16(ps[s*4 + 0], ps[s*4 + 1]);
        pk[s][1] = cvtpk_bf16(ps[s*4 + 2], ps[s*4 + 3]);
      }
#pragma unroll
      for (int ksl = 0; ksl < 2; ksl++) {
        uint2v s0 = __builtin_amdgcn_permlane32_swap(pk[2*ksl][0], pk[2*ksl + 1][0], false, false);
        uint2v s1 = __builtin_amdgcn_permlane32_swap(pk[2*ksl][1], pk[2*ksl + 1][1], false, false);
        uint4v fu;
        fu[0] = s0.x; fu[1] = s1.x; fu[2] = s0.y; fu[3] = s1.y;
        short8 pfrag = *(short8*)&fu;

        __builtin_amdgcn_s_setprio(1);
        {
          short8 vf = *(const short8*)((const char*)Vs + voff[kb][ksl][0]);
          oacc0 = MFMA32_BF16(pfrag, vf, oacc0);
        }
        {
          short8 vf = *(const short8*)((const char*)Vs + voff[kb][ksl][1]);
          oacc1 = MFMA32_BF16(pfrag, vf, oacc1);
        }
        nacc = MFMA32_BF16(pfrag, ones8, nacc);
        __builtin_amdgcn_s_setprio(0);
      }
    }
  };

  // prologue: stage tile 0 into buf 0; preload mask words for tile 0
  attn_stage(KB, VB, lds, lds + 8192, 0, w, l);
  uint2v wd = *(const uint2v*)&mrow[0];
  asm volatile("s_waitcnt vmcnt(0)" ::: "memory");
  __builtin_amdgcn_s_barrier();
  asm volatile("" ::: "memory");

  // kt unrolled by 2: even tiles in buf0 (lds, lds+8192), odd in buf1 (+4096)
  for (int t2 = 0; t2 < 16; t2++) {
    // stage odd tile 2*t2+1 into buf1 (always valid: 2*t2+1 <= 31)
    attn_stage(KB, VB, lds + 4096, lds + 12288, (2*t2 + 1)*64, w, l);
    uint2v wdB = *(const uint2v*)&mrow[(2*t2 + 1)*2];

    do_tile(lds, lds + 8192, wd);                 // even tile from buf0

    asm volatile("s_waitcnt vmcnt(0)" ::: "memory");
    __builtin_amdgcn_s_barrier();
    asm volatile("" ::: "memory");

    uint2v wdN = wd;
    if (t2 < 15) {
      attn_stage(KB, VB, lds, lds + 8192, (2*t2 + 2)*64, w, l);
      wdN = *(const uint2v*)&mrow[(2*t2 + 2)*2];
    }

    do_tile(lds + 4096, lds + 12288, wdB);        // odd tile from buf1
    wd = wdN;

    asm volatile("s_waitcnt vmcnt(0)" ::: "memory");
    __builtin_amdgcn_s_barrier();
    asm volatile("" ::: "memory");
  }

  // output: O[q = qw + (t&3)+8*(t>>2)+4h][d], col = hd*64 + db*32 + c5
#pragma unroll
  for (int t = 0; t < 16; t++) {
    float iv = 1.0f / nacc[t];
    int qrow = qw + (t & 3) + 8*(t >> 2) + hv;
    unsigned short* orow = &cat[(b*2048 + qrow)*1024 + hd*64];
    orow[c5]      = (unsigned short)f2bf(oacc0[t] * iv);
    orow[32 + c5] = (unsigned short)f2bf(oacc1[t] * iv);
  }
}

// ---------------- standalone attn (fallback path) ----------------
__global__ __launch_bounds__(256, 4)
void attn_kernel(const unsigned short* __restrict__ Q, const unsigned short* __restrict__ Kb,
                 const unsigned short* __restrict__ VT, const unsigned* __restrict__ mp,
                 unsigned short* __restrict__ cat)
{
  __shared__ short lds[16384];
  attn_body(blockIdx.x, lds, Q, Kb, VT, mp, cat);
}

// ---------------- FUSED: gemm_c (bf16 adj) + attn ----------------
__global__ __launch_bounds__(256, 4)
void fused_ca_kernel(const unsigned short* __restrict__ adjb, const unsigned short* __restrict__ xgT,
                     const unsigned short* __restrict__ Q, const unsigned short* __restrict__ Kb,
                     const unsigned short* __restrict__ VT, const unsigned* __restrict__ mp,
                     unsigned short* __restrict__ cat)
{
  __shared__ short lds[16384];
  int bid = blockIdx.x;
  int r3 = bid % 3;
  if (r3 == 2) {
    int cbid = bid / 3;
    int tid = threadIdx.x, w = tid >> 6, l = tid & 63;
    int xcd = cbid & 7, slot = cbid >> 3;
    int p  = xcd + ((slot >> 2) << 3);
    int nt = slot & 3;
    int b = p >> 4, mt = p & 15;
    int rows0 = mt*128, cols0 = nt*128;

    floatx4 acc[4][4];
    const floatx4 zf = {0.f, 0.f, 0.f, 0.f};
#pragma unroll
    for (int a2 = 0; a2 < 4; a2++)
#pragma unroll
      for (int b2 = 0; b2 < 4; b2++) acc[a2][b2] = zf;

    gemm_kloop_bf16(adjb + (size_t)b*2048*2048 + (size_t)rows0*2048, 2048,
                    xgT + (b*512 + cols0)*2048, 2048, 2048,
                    lds, lds + 4096, w, l, acc);

    int wr = (w >> 1)*64, wc = (w & 1)*64;
#pragma unroll
    for (int mi = 0; mi < 4; mi++)
#pragma unroll
      for (int bi = 0; bi < 4; bi++)
#pragma unroll
        for (int r = 0; r < 4; r++) {
          int rowg = b*2048 + rows0 + wr + mi*16 + ((l >> 4) << 2) + r;
          int col  = 512 + cols0 + wc + bi*16 + (l & 15);
          cat[rowg*1024 + col] = (unsigned short)f2bf(acc[mi][bi][r]);
        }
  } else {
    int abid = (bid / 3)*2 + r3;
    attn_body(abid, lds, Q, Kb, VT, mp, cat);
  }
}

// ---------------- GEMM-D: out = cat @ W_out + b_out (fp32 out) ----------------
__global__ __launch_bounds__(256, 2)
void gemm_d_kernel(const unsigned short* __restrict__ cat, const unsigned short* __restrict__ woutT,
                   const float* __restrict__ bout, float* __restrict__ out)
{
  __shared__ short lds[8192];
  int tid = threadIdx.x, w = tid >> 6, l = tid & 63;
  int bid = blockIdx.x;
  int xcd = bid & 7, slot = bid >> 3;
  int p  = xcd + ((slot >> 2) << 3);
  int nt = slot & 3;
  int rows0 = p*128, cols0 = nt*128;

  floatx4 acc[4][4];
  const floatx4 zf = {0.f, 0.f, 0.f, 0.f};
#pragma unroll
  for (int a2 = 0; a2 < 4; a2++)
#pragma unroll
    for (int b2 = 0; b2 < 4; b2++) acc[a2][b2] = zf;

  gemm_kloop_bf16(cat + (size_t)rows0*1024, 1024, woutT + cols0*1024, 1024, 1024,
                  lds, lds + 4096, w, l, acc);

  int wr = (w >> 1)*64, wc = (w & 1)*64;
#pragma unroll
  for (int bi = 0; bi < 4; bi++) {
    int col = cols0 + wc + bi*16 + (l & 15);
    float bias = bout[col];
#pragma unroll
    for (int mi = 0; mi < 4; mi++)
#pragma unroll
      for (int r = 0; r < 4; r++) {
        int rowg = rows0 + wr + mi*16 + ((l >> 4) << 2) + r;
        out[rowg*512 + col] = acc[mi][bi][r] + bias;
      }
  }
}

// ---------------- launch ----------------
extern "C" void kernel_launch(void* const* d_in, const int* in_sizes, int n_in,
                              void* d_out, int out_size, void* d_ws, size_t ws_size,
                              hipStream_t stream)
{
  (void)in_sizes; (void)n_in; (void)out_size;
  const float* x   = (const float*)d_in[0];
  const float* adj = (const float*)d_in[1];
  const void*  msk = d_in[2];
  const float* wg  = (const float*)d_in[3];
  const float* wq  = (const float*)d_in[4];
  const float* wo  = (const float*)d_in[5];
  const float* bo  = (const float*)d_in[6];
  float* out = (float*)d_out;
  char* ws = (char*)d_ws;

  unsigned short* xbf   = (unsigned short*)(ws + 0);          // 16,777,216
  unsigned short* wcat  = (unsigned short*)(ws + 16777216);   //  2,097,152
  unsigned short* woutT = (unsigned short*)(ws + 18874368);   //  1,048,576
  unsigned short* xgT   = (unsigned short*)(ws + 19922944);   // 16,777,216
  unsigned short* Qb    = (unsigned short*)(ws + 36700160);   // 16,777,216
  unsigned short* Kb    = (unsigned short*)(ws + 53477376);   // 16,777,216
  unsigned short* VTb   = (unsigned short*)(ws + 70254592);   // 16,777,216
  unsigned short* cat   = (unsigned short*)(ws + 87031808);   // 33,554,432
  unsigned*       mp    = (unsigned*)(ws + 120586240);        //  4,194,304
  unsigned*       flag  = (unsigned*)(ws + 124780544);        //         64
  unsigned short* adjb  = (unsigned short*)(ws + 124780608);  // 67,108,864 (optional)

  const int use_adjb = (ws_size >= (size_t)124780608 + 67108864) ? 1 : 0;

  detect_kernel<<<1, 256, 0, stream>>>((const unsigned char*)msk, flag);
  if (use_adjb) {
    prep_small_kernel<<<14336, 256, 0, stream>>>(x, wg, wq, wo, xbf, wcat, woutT);
    gemm_ab_kernel<<<22528, 256, 0, stream>>>(xbf, wcat, xgT, Qb, Kb, VTb,
                                              msk, flag, adj, mp, adjb, 1);
    fused_ca_kernel<<<1536, 256, 0, stream>>>(adjb, xgT, Qb, Kb, VTb, mp, cat);
  } else {
    prep_full_kernel<<<145408, 256, 0, stream>>>(x, wg, wq, wo, msk, flag,
                                                 xbf, wcat, woutT, mp);
    gemm_ab_kernel<<<2048, 256, 0, stream>>>(xbf, wcat, xgT, Qb, Kb, VTb,
                                             msk, flag, adj, mp, adjb, 0);
    gemm_c_f32_kernel<<<512, 256, 0, stream>>>(adj, xgT, cat);
    attn_kernel<<<1024, 256, 0, stream>>>(Qb, Kb, VTb, mp, cat);
  }
  gemm_d_kernel<<<512, 256, 0, stream>>>(cat, woutT, bo, out);
}

// Round 16
// 361.686 us; speedup vs baseline: 2.8137x; 1.0041x over previous
//
#include <hip/hip_runtime.h>
#include <stdint.h>

#define DEVFN __device__ __forceinline__

typedef __attribute__((ext_vector_type(8))) short short8;
typedef __attribute__((ext_vector_type(4))) short short4v;
typedef __attribute__((ext_vector_type(4))) float floatx4;
typedef __attribute__((ext_vector_type(16))) float floatx16;
typedef __attribute__((ext_vector_type(4))) float vfloat4;
typedef __attribute__((ext_vector_type(2))) unsigned int uint2v;
typedef __attribute__((ext_vector_type(4))) unsigned int uint4v;

#define MFMA_BF16(a,b,c) __builtin_amdgcn_mfma_f32_16x16x32_bf16((a),(b),(c),0,0,0)
#define MFMA32_BF16(a,b,c) __builtin_amdgcn_mfma_f32_32x32x16_bf16((a),(b),(c),0,0,0)
#define GL2LDS(g,l) __builtin_amdgcn_global_load_lds((const __attribute__((address_space(1))) void*)(g), (__attribute__((address_space(3))) void*)(l), 16, 0, 0)

DEVFN unsigned short f2bf(float f){
  unsigned u = __float_as_uint(f);
  u = (u + 0x7fffu + ((u >> 16) & 1u)) >> 16;
  return (unsigned short)u;
}

DEVFN unsigned cvtpk_bf16(float lo, float hi){
  unsigned r;
  asm("v_cvt_pk_bf16_f32 %0, %1, %2" : "=v"(r) : "v"(lo), "v"(hi));
  return r;
}

// ---------------- mask dtype detection ----------------
__global__ void detect_kernel(const unsigned char* m, unsigned int* flag){
  if (threadIdx.x == 0) *flag = 0u;
  __syncthreads();
  int any = 0;
  for (int i = threadIdx.x; i < 4096; i += 256)
    if ((i & 3) != 0 && m[i]) any = 1;
  if (any) atomicOr(flag, 1u);
}

// ---------------- prep (small): x->bf16, weightsT->bf16 (Q pre-scaled) ----------------
__global__ void prep_small_kernel(const float* __restrict__ x, const float* __restrict__ wg,
                                  const float* __restrict__ wq, const float* __restrict__ wo,
                                  unsigned short* __restrict__ xbf, unsigned short* __restrict__ wcat,
                                  unsigned short* __restrict__ woutT)
{
  int bid = blockIdx.x, tid = threadIdx.x;
  if (bid < 8192) {                               // x -> bf16
    int i = (bid*256 + tid)*4;
    vfloat4 v = *(const vfloat4*)&x[i];
    short4v c; c[0]=(short)f2bf(v[0]); c[1]=(short)f2bf(v[1]); c[2]=(short)f2bf(v[2]); c[3]=(short)f2bf(v[3]);
    *(short4v*)&xbf[i] = c;
  } else if (bid < 12288) {                       // WcatT (Q cols pre-scaled by 0.125*log2e)
    int i = (bid - 8192)*256 + tid;
    int k = i & 511, c = i >> 9;
    float v = (c < 512) ? wg[k*512 + c] : wq[k*1536 + (c - 512)];
    if (c >= 512 && c < 1024) v *= 0.18033688f;
    wcat[c*512 + k] = (unsigned short)f2bf(v);
  } else {                                        // WoutT
    int i = (bid - 12288)*256 + tid;
    int k = i & 1023, n2 = i >> 10;
    woutT[n2*1024 + k] = (unsigned short)f2bf(wo[k*512 + n2]);
  }
}

// ---------------- prep (full, fallback path only) ----------------
__global__ void prep_full_kernel(const float* __restrict__ x, const float* __restrict__ wg,
                                 const float* __restrict__ wq, const float* __restrict__ wo,
                                 const void* __restrict__ mask, const unsigned* __restrict__ flag,
                                 unsigned short* __restrict__ xbf, unsigned short* __restrict__ wcat,
                                 unsigned short* __restrict__ woutT, unsigned* __restrict__ mp)
{
  int bid = blockIdx.x, tid = threadIdx.x;
  if (bid < 8192) {
    int i = (bid*256 + tid)*4;
    vfloat4 v = *(const vfloat4*)&x[i];
    short4v c; c[0]=(short)f2bf(v[0]); c[1]=(short)f2bf(v[1]); c[2]=(short)f2bf(v[2]); c[3]=(short)f2bf(v[3]);
    *(short4v*)&xbf[i] = c;
  } else if (bid < 12288) {
    int i = (bid - 8192)*256 + tid;
    int k = i & 511, c = i >> 9;
    float v = (c < 512) ? wg[k*512 + c] : wq[k*1536 + (c - 512)];
    if (c >= 512 && c < 1024) v *= 0.18033688f;
    wcat[c*512 + k] = (unsigned short)f2bf(v);
  } else if (bid < 14336) {
    int i = (bid - 12288)*256 + tid;
    int k = i & 1023, n2 = i >> 10;
    woutT[n2*1024 + k] = (unsigned short)f2bf(wo[k*512 + n2]);
  } else {                                        // mask bit-pack
    int j = bid - 14336;
    int e = j*256 + tid;
    int v;
    if (*flag) v = ((const unsigned char*)mask)[e];
    else       v = ((const int*)mask)[e];
    unsigned long long ball = __ballot(v != 0);
    int base = e & ~63;
    int lane = tid & 63;
    if (lane == 0)  mp[(base >> 5) + 0] = (unsigned)(ball & 0xffffffffull);
    if (lane == 32) mp[(base >> 5) + 1] = (unsigned)(ball >> 32);
  }
}

// ---------------- shared 128x128 BK=32 bf16 K-loop (m97 structure) ----------------
DEVFN void gemm_kloop_bf16(const unsigned short* Ag, int lda,
                           const unsigned short* Bg, int ldb, int K,
                           short* As, short* Bs, int w, int l,
                           floatx4 (&acc)[4][4])
{
  const int wr = (w >> 1)*64, wc = (w & 1)*64;
  for (int k0 = 0; k0 < K; k0 += 32) {
    __syncthreads();
#pragma unroll
    for (int i = 0; i < 2; i++) {
      int id = (w*2 + i)*64 + l;
      int row = id >> 2, part = id & 3;
      GL2LDS(Ag + row*lda + k0 + part*8, As + (w*2 + i)*512);
      GL2LDS(Bg + row*ldb + k0 + part*8, Bs + (w*2 + i)*512);
    }
    __syncthreads();
    short8 af[4], bfr[4];
#pragma unroll
    for (int t = 0; t < 4; t++) {
      af[t]  = *(const short8*)&As[(wr + t*16 + (l & 15))*32 + ((l >> 4) << 3)];
      bfr[t] = *(const short8*)&Bs[(wc + t*16 + (l & 15))*32 + ((l >> 4) << 3)];
    }
#pragma unroll
    for (int a2 = 0; a2 < 4; a2++)
#pragma unroll
      for (int b2 = 0; b2 < 4; b2++)
        acc[a2][b2] = MFMA_BF16(af[a2], bfr[b2], acc[a2][b2]);
  }
}

// ---------------- GEMM-AB (+ pipelined BW blocks): xgT/Q/K/VT ; mask pack ; adj->bf16 ----------------
__global__ __launch_bounds__(256, 2)
void gemm_ab_kernel(const unsigned short* __restrict__ xbf, const unsigned short* __restrict__ wcat,
                    unsigned short* __restrict__ xgT, unsigned short* __restrict__ Qo,
                    unsigned short* __restrict__ Ko, unsigned short* __restrict__ VTo,
                    const void* __restrict__ mask, const unsigned* __restrict__ flag,
                    const float* __restrict__ adj,
                    unsigned* __restrict__ mp, unsigned short* __restrict__ adjb,
                    int mode)
{
  __shared__ short lds[16384];
  int tid = threadIdx.x, w = tid >> 6, l = tid & 63;
  int bid = blockIdx.x;

  int gemmid;
  if (mode) {
    int r11 = bid % 11, g11 = bid / 11;
    if (r11 != 0) {
      int bw = g11*10 + (r11 - 1);                // 0..20479
      if (bw < 16384) {
        unsigned fl = *flag;
        int lane = tid & 63;
        int vv[8];
        if (fl) {
          const unsigned char* m8 = (const unsigned char*)mask;
#pragma unroll
          for (int j = 0; j < 8; j++) vv[j] = m8[(bw*8 + j)*256 + tid];
        } else {
          const int* m32 = (const int*)mask;
#pragma unroll
          for (int j = 0; j < 8; j++) vv[j] = m32[(bw*8 + j)*256 + tid];
        }
#pragma unroll
        for (int j = 0; j < 8; j++) {
          unsigned long long ball = __ballot(vv[j] != 0);
          int e = (bw*8 + j)*256 + tid;
          int base = e & ~63;
          if (lane == 0)  mp[(base >> 5) + 0] = (unsigned)(ball & 0xffffffffull);
          if (lane == 32) mp[(base >> 5) + 1] = (unsigned)(ball >> 32);
        }
      } else {
        int ab = bw - 16384;
        vfloat4 vv[8];
#pragma unroll
        for (int j = 0; j < 8; j++)
          vv[j] = *(const vfloat4*)&adj[((ab*8 + j)*256 + tid)*4];
#pragma unroll
        for (int j = 0; j < 8; j++) {
          short4v c; c[0]=(short)f2bf(vv[j][0]); c[1]=(short)f2bf(vv[j][1]);
          c[2]=(short)f2bf(vv[j][2]); c[3]=(short)f2bf(vv[j][3]);
          *(short4v*)&adjb[((ab*8 + j)*256 + tid)*4] = c;
        }
      }
      return;
    }
    gemmid = g11;                                 // 0..2047
  } else {
    gemmid = bid;
  }

  int xcd = gemmid & 7, slot = gemmid >> 3;
  int p  = xcd + ((slot >> 4) << 3);
  int nt = slot & 15;
  int rows0 = p*128, cols0 = nt*128;

  floatx4 acc[4][4];
  const floatx4 zf = {0.f, 0.f, 0.f, 0.f};
#pragma unroll
  for (int a2 = 0; a2 < 4; a2++)
#pragma unroll
    for (int b2 = 0; b2 < 4; b2++) acc[a2][b2] = zf;

  gemm_kloop_bf16(xbf + rows0*512, 512, wcat + cols0*512, 512, 512,
                  lds, lds + 4096, w, l, acc);
  __syncthreads();

  int wr = (w >> 1)*64, wc = (w & 1)*64;
  int b = p >> 4;
  int n0 = (p & 15)*128 + wr;
  int gc0 = cols0 + wc;

  if (nt < 4 || nt >= 12) {
    short* T = lds + w*4096;
#pragma unroll
    for (int mi = 0; mi < 4; mi++)
#pragma unroll
      for (int bi = 0; bi < 4; bi++)
#pragma unroll
        for (int r = 0; r < 4; r++) {
          int rl = mi*16 + ((l >> 4) << 2) + r;
          int cl = bi*16 + (l & 15);
          T[cl*64 + ((((rl >> 3) ^ (cl & 7))) << 3) + (rl & 7)] = (short)f2bf(acc[mi][bi][r]);
        }
#pragma unroll
    for (int i = 0; i < 8; i++) {
      int chunk = i*64 + l;
      int c = chunk >> 3, s = chunk & 7;
      short8 v = *(const short8*)&T[c*64 + ((s ^ (c & 7)) << 3)];
      int rowstart = n0 + s*8;
      if (nt < 4) {
        int d = gc0 + c;
        *(short8*)&xgT[(b*512 + d)*2048 + rowstart] = v;
      } else {
        int vc = gc0 + c - 1536;
        int hh = vc >> 6, dd = vc & 63;
        *(short8*)&VTo[((b*8 + hh)*64 + dd)*2048 + rowstart] = v;
      }
    }
  } else {
    unsigned short* dst = (nt < 8) ? Qo : Ko;
    int cbase = gc0 - ((nt < 8) ? 512 : 1024);
    int hh = cbase >> 6;
#pragma unroll
    for (int mi = 0; mi < 4; mi++)
#pragma unroll
      for (int bi = 0; bi < 4; bi++)
#pragma unroll
        for (int r = 0; r < 4; r++) {
          int rowg = n0 + mi*16 + ((l >> 4) << 2) + r;
          int dd = bi*16 + (l & 15);
          dst[((b*8 + hh)*2048 + rowg)*64 + dd] = (unsigned short)f2bf(acc[mi][bi][r]);
        }
  }
}

// ---------------- GEMM-C (fp32 fallback, original) ----------------
__global__ __launch_bounds__(256, 2)
void gemm_c_f32_kernel(const float* __restrict__ adj, const unsigned short* __restrict__ xgT,
                       unsigned short* __restrict__ cat)
{
  __shared__ short lds[8192];
  int tid = threadIdx.x, w = tid >> 6, l = tid & 63;
  int bid = blockIdx.x;
  int xcd = bid & 7, slot = bid >> 3;
  int p  = xcd + ((slot >> 2) << 3);
  int nt = slot & 3;
  int b = p >> 4, mt = p & 15;
  int rows0 = mt*128, cols0 = nt*128;
  const float* Ag = adj + (size_t)b*2048*2048 + (size_t)rows0*2048;
  const unsigned short* Bg = xgT + (b*512 + cols0)*2048;

  floatx4 acc[4][4];
  const floatx4 zf = {0.f, 0.f, 0.f, 0.f};
#pragma unroll
  for (int a2 = 0; a2 < 4; a2++)
#pragma unroll
    for (int b2 = 0; b2 < 4; b2++) acc[a2][b2] = zf;

  const int wr = (w >> 1)*64, wc = (w & 1)*64;
  for (int k0 = 0; k0 < 2048; k0 += 32) {
    __syncthreads();
#pragma unroll
    for (int i = 0; i < 4; i++) {
      int id = (w*4 + i)*64 + l;
      int row = id >> 3, part = id & 7;
      vfloat4 v = *(const vfloat4*)&Ag[row*2048 + k0 + part*4];
      short4v c4; c4[0]=(short)f2bf(v[0]); c4[1]=(short)f2bf(v[1]); c4[2]=(short)f2bf(v[2]); c4[3]=(short)f2bf(v[3]);
      *(short4v*)&lds[row*32 + part*4] = c4;
    }
#pragma unroll
    for (int i = 0; i < 2; i++) {
      int id = (w*2 + i)*64 + l;
      int row = id >> 2, part = id & 3;
      GL2LDS(Bg + row*2048 + k0 + part*8, lds + 4096 + (w*2 + i)*512);
    }
    __syncthreads();
    short8 af[4], bfr[4];
#pragma unroll
    for (int t = 0; t < 4; t++) {
      af[t]  = *(const short8*)&lds[(wr + t*16 + (l & 15))*32 + ((l >> 4) << 3)];
      bfr[t] = *(const short8*)&lds[4096 + (wc + t*16 + (l & 15))*32 + ((l >> 4) << 3)];
    }
#pragma unroll
    for (int a2 = 0; a2 < 4; a2++)
#pragma unroll
      for (int b2 = 0; b2 < 4; b2++)
        acc[a2][b2] = MFMA_BF16(af[a2], bfr[b2], acc[a2][b2]);
  }

#pragma unroll
  for (int mi = 0; mi < 4; mi++)
#pragma unroll
    for (int bi = 0; bi < 4; bi++)
#pragma unroll
      for (int r = 0; r < 4; r++) {
        int rowg = b*2048 + rows0 + wr + mi*16 + ((l >> 4) << 2) + r;
        int col  = 512 + cols0 + wc + bi*16 + (l & 15);
        cat[rowg*1024 + col] = (unsigned short)f2bf(acc[mi][bi][r]);
      }
}

// ---------------- attn tile body (v8: static LDS offsets, kt unrolled x2) ----------------
DEVFN void attn_stage(const unsigned short* KB, const unsigned short* VB,
                      short* Ks, short* Vs, int kn0, int w, int l)
{
#pragma unroll
  for (int i = 0; i < 2; i++) {
    int id = (w*2 + i)*64 + l;
    int row = id >> 3, sl = id & 7;
    int sp = sl ^ (row & 7) ^ (((row >> 3) & 3) << 1);
    GL2LDS(KB + (kn0 + row)*64 + sp*8, Ks + (w*2 + i)*512);
    GL2LDS(VB + row*2048 + kn0 + sp*8, Vs + (w*2 + i)*512);
  }
}

DEVFN void attn_body(int abid, short* lds,
                     const unsigned short* __restrict__ Q, const unsigned short* __restrict__ Kb,
                     const unsigned short* __restrict__ VT, const unsigned* __restrict__ mp,
                     unsigned short* __restrict__ cat)
{
  int tid = threadIdx.x, w = tid >> 6, l = tid & 63;
  int c5 = l & 31, h = l >> 5;
  int hv = h*4;

  int xcd = abid & 7, slot = abid >> 3;
  int bh = xcd + ((slot >> 4) << 3);              // 0..63
  int qt = slot & 15;
  int b = bh >> 3, hd = bh & 7;
  int qw = qt*128 + w*32;

  const unsigned short* Qb = Q  + (size_t)bh*2048*64;
  const unsigned short* KB = Kb + (size_t)bh*2048*64;
  const unsigned short* VB = VT + (size_t)bh*64*2048;
  const unsigned* mrow = mp + b*2048*64 + (qw + c5)*64;

  short8 qf[4];
#pragma unroll
  for (int dk = 0; dk < 4; dk++)
    qf[dk] = *(const short8*)&Qb[(qw + c5)*64 + dk*16 + h*8];

  // loop-invariant swizzled LDS byte-offsets (static after unroll)
  int koff[2][4], voff[2][2][2];
#pragma unroll
  for (int kb = 0; kb < 2; kb++) {
    int row = kb*32 + c5;
    int rsw = (row & 7) ^ (((row >> 3) & 3) << 1);
#pragma unroll
    for (int dk = 0; dk < 4; dk++)
      koff[kb][dk] = (row*64 + (((dk*2 + h) ^ rsw) << 3))*2;
  }
#pragma unroll
  for (int db = 0; db < 2; db++) {
    int vrow = db*32 + c5;
    int vsw = (vrow & 7) ^ (((vrow >> 3) & 3) << 1);
#pragma unroll
    for (int kb = 0; kb < 2; kb++)
#pragma unroll
      for (int ksl = 0; ksl < 2; ksl++)
        voff[kb][ksl][db] = (vrow*64 + (((kb*4 + ksl*2 + h) ^ vsw) << 3))*2;
  }

  floatx16 oacc0, oacc1, nacc;
  const floatx16 zf16 = {0.f,0.f,0.f,0.f,0.f,0.f,0.f,0.f,0.f,0.f,0.f,0.f,0.f,0.f,0.f,0.f};
  oacc0 = zf16; oacc1 = zf16; nacc = zf16;

  const short8 ones8 = {(short)0x3F80,(short)0x3F80,(short)0x3F80,(short)0x3F80,
                        (short)0x3F80,(short)0x3F80,(short)0x3F80,(short)0x3F80}; // bf16 1.0

  auto do_tile = [&](const short* Ks, const short* Vs, uint2v wdt) {
#pragma unroll
    for (int kb = 0; kb < 2; kb++) {
      floatx16 sacc;
      __builtin_amdgcn_s_setprio(1);
      {
        short8 kf = *(const short8*)((const char*)Ks + koff[kb][0]);
        sacc = MFMA32_BF16(kf, qf[0], zf16);      // fused zero-init
      }
#pragma unroll
      for (int dk = 1; dk < 4; dk++) {
        short8 kf = *(const short8*)((const char*)Ks + koff[kb][dk]);
        sacc = MFMA32_BF16(kf, qf[dk], sacc);
      }
      __builtin_amdgcn_s_setprio(0);

      unsigned keep = ~((kb ? wdt.y : wdt.x) >> hv);
      float ps[16];
#pragma unroll
      for (int t = 0; t < 16; t++) {
        int pos = (t >> 2)*8 + (t & 3);
        int keepm = __builtin_amdgcn_sbfe((int)keep, pos, 1);  // -1 keep, 0 masked
        float p = exp2f(sacc[t]);
        ps[t] = __uint_as_float(__float_as_uint(p) & (unsigned)keepm);
      }
      unsigned pk[4][2];
#pragma unroll
      for (int s = 0; s < 4; s++) {
        pk[s][0] = cvtpk_bf16(ps[s*4 + 0], ps[s*4 + 1]);
        pk[s][1] = cvtpk_bf16(ps[s*4 + 2], ps[s*4 + 3]);
      }
#pragma unroll
      for (int ksl = 0; ksl < 2; ksl++) {
        uint2v s0 = __builtin_amdgcn_permlane32_swap(pk[2*ksl][0], pk[2*ksl + 1][0], false, false);
        uint2v s1 = __builtin_amdgcn_permlane32_swap(pk[2*ksl][1], pk[2*ksl + 1][1], false, false);
        uint4v fu;
        fu[0] = s0.x; fu[1] = s1.x; fu[2] = s0.y; fu[3] = s1.y;
        short8 pfrag = *(short8*)&fu;

        __builtin_amdgcn_s_setprio(1);
        {
          short8 vf = *(const short8*)((const char*)Vs + voff[kb][ksl][0]);
          oacc0 = MFMA32_BF16(pfrag, vf, oacc0);
        }
        {
          short8 vf = *(const short8*)((const char*)Vs + voff[kb][ksl][1]);
          oacc1 = MFMA32_BF16(pfrag, vf, oacc1);
        }
        nacc = MFMA32_BF16(pfrag, ones8, nacc);
        __builtin_amdgcn_s_setprio(0);
      }
    }
  };

  // prologue: stage tile 0 into buf 0; preload mask words for tile 0
  attn_stage(KB, VB, lds, lds + 8192, 0, w, l);
  uint2v wd = *(const uint2v*)&mrow[0];
  asm volatile("s_waitcnt vmcnt(0)" ::: "memory");
  __builtin_amdgcn_s_barrier();
  asm volatile("" ::: "memory");

  // kt unrolled by 2: even tiles in buf0 (lds, lds+8192), odd in buf1 (+4096)
  for (int t2 = 0; t2 < 16; t2++) {
    attn_stage(KB, VB, lds + 4096, lds + 12288, (2*t2 + 1)*64, w, l);
    uint2v wdB = *(const uint2v*)&mrow[(2*t2 + 1)*2];

    do_tile(lds, lds + 8192, wd);                 // even tile from buf0

    asm volatile("s_waitcnt vmcnt(0)" ::: "memory");
    __builtin_amdgcn_s_barrier();
    asm volatile("" ::: "memory");

    uint2v wdN = wd;
    if (t2 < 15) {
      attn_stage(KB, VB, lds, lds + 8192, (2*t2 + 2)*64, w, l);
      wdN = *(const uint2v*)&mrow[(2*t2 + 2)*2];
    }

    do_tile(lds + 4096, lds + 12288, wdB);        // odd tile from buf1
    wd = wdN;

    asm volatile("s_waitcnt vmcnt(0)" ::: "memory");
    __builtin_amdgcn_s_barrier();
    asm volatile("" ::: "memory");
  }

  // output: O[q = qw + (t&3)+8*(t>>2)+4h][d], col = hd*64 + db*32 + c5
#pragma unroll
  for (int t = 0; t < 16; t++) {
    float iv = 1.0f / nacc[t];
    int qrow = qw + (t & 3) + 8*(t >> 2) + hv;
    unsigned short* orow = &cat[(b*2048 + qrow)*1024 + hd*64];
    orow[c5]      = (unsigned short)f2bf(oacc0[t] * iv);
    orow[32 + c5] = (unsigned short)f2bf(oacc1[t] * iv);
  }
}

// ---------------- standalone attn (fallback path) ----------------
__global__ __launch_bounds__(256, 4)
void attn_kernel(const unsigned short* __restrict__ Q, const unsigned short* __restrict__ Kb,
                 const unsigned short* __restrict__ VT, const unsigned* __restrict__ mp,
                 unsigned short* __restrict__ cat)
{
  __shared__ short lds[16384];
  attn_body(blockIdx.x, lds, Q, Kb, VT, mp, cat);
}

// ---------------- FUSED: gemm_c (bf16 adj) + attn; gemm tiles dispatched FIRST in each triple ----------------
__global__ __launch_bounds__(256, 4)
void fused_ca_kernel(const unsigned short* __restrict__ adjb, const unsigned short* __restrict__ xgT,
                     const unsigned short* __restrict__ Q, const unsigned short* __restrict__ Kb,
                     const unsigned short* __restrict__ VT, const unsigned* __restrict__ mp,
                     unsigned short* __restrict__ cat)
{
  __shared__ short lds[16384];
  int bid = blockIdx.x;
  int r3 = bid % 3;
  if (r3 == 0) {
    // ---- gemm_c tile (512 tiles, the long pole — start earliest) ----
    int cbid = bid / 3;
    int tid = threadIdx.x, w = tid >> 6, l = tid & 63;
    int xcd = cbid & 7, slot = cbid >> 3;
    int p  = xcd + ((slot >> 2) << 3);
    int nt = slot & 3;
    int b = p >> 4, mt = p & 15;
    int rows0 = mt*128, cols0 = nt*128;

    floatx4 acc[4][4];
    const floatx4 zf = {0.f, 0.f, 0.f, 0.f};
#pragma unroll
    for (int a2 = 0; a2 < 4; a2++)
#pragma unroll
      for (int b2 = 0; b2 < 4; b2++) acc[a2][b2] = zf;

    gemm_kloop_bf16(adjb + (size_t)b*2048*2048 + (size_t)rows0*2048, 2048,
                    xgT + (b*512 + cols0)*2048, 2048, 2048,
                    lds, lds + 4096, w, l, acc);

    int wr = (w >> 1)*64, wc = (w & 1)*64;
#pragma unroll
    for (int mi = 0; mi < 4; mi++)
#pragma unroll
      for (int bi = 0; bi < 4; bi++)
#pragma unroll
        for (int r = 0; r < 4; r++) {
          int rowg = b*2048 + rows0 + wr + mi*16 + ((l >> 4) << 2) + r;
          int col  = 512 + cols0 + wc + bi*16 + (l & 15);
          cat[rowg*1024 + col] = (unsigned short)f2bf(acc[mi][bi][r]);
        }
  } else {
    int abid = (bid / 3)*2 + (r3 - 1);
    attn_body(abid, lds, Q, Kb, VT, mp, cat);
  }
}

// ---------------- GEMM-D: out = cat @ W_out + b_out (fp32 out) ----------------
__global__ __launch_bounds__(256, 2)
void gemm_d_kernel(const unsigned short* __restrict__ cat, const unsigned short* __restrict__ woutT,
                   const float* __restrict__ bout, float* __restrict__ out)
{
  __shared__ short lds[8192];
  int tid = threadIdx.x, w = tid >> 6, l = tid & 63;
  int bid = blockIdx.x;
  int xcd = bid & 7, slot = bid >> 3;
  int p  = xcd + ((slot >> 2) << 3);
  int nt = slot & 3;
  int rows0 = p*128, cols0 = nt*128;

  floatx4 acc[4][4];
  const floatx4 zf = {0.f, 0.f, 0.f, 0.f};
#pragma unroll
  for (int a2 = 0; a2 < 4; a2++)
#pragma unroll
    for (int b2 = 0; b2 < 4; b2++) acc[a2][b2] = zf;

  gemm_kloop_bf16(cat + (size_t)rows0*1024, 1024, woutT + cols0*1024, 1024, 1024,
                  lds, lds + 4096, w, l, acc);

  int wr = (w >> 1)*64, wc = (w & 1)*64;
#pragma unroll
  for (int bi = 0; bi < 4; bi++) {
    int col = cols0 + wc + bi*16 + (l & 15);
    float bias = bout[col];
#pragma unroll
    for (int mi = 0; mi < 4; mi++)
#pragma unroll
      for (int r = 0; r < 4; r++) {
        int rowg = rows0 + wr + mi*16 + ((l >> 4) << 2) + r;
        out[rowg*512 + col] = acc[mi][bi][r] + bias;
      }
  }
}

// ---------------- launch ----------------
extern "C" void kernel_launch(void* const* d_in, const int* in_sizes, int n_in,
                              void* d_out, int out_size, void* d_ws, size_t ws_size,
                              hipStream_t stream)
{
  (void)in_sizes; (void)n_in; (void)out_size;
  const float* x   = (const float*)d_in[0];
  const float* adj = (const float*)d_in[1];
  const void*  msk = d_in[2];
  const float* wg  = (const float*)d_in[3];
  const float* wq  = (const float*)d_in[4];
  const float* wo  = (const float*)d_in[5];
  const float* bo  = (const float*)d_in[6];
  float* out = (float*)d_out;
  char* ws = (char*)d_ws;

  unsigned short* xbf   = (unsigned short*)(ws + 0);          // 16,777,216
  unsigned short* wcat  = (unsigned short*)(ws + 16777216);   //  2,097,152
  unsigned short* woutT = (unsigned short*)(ws + 18874368);   //  1,048,576
  unsigned short* xgT   = (unsigned short*)(ws + 19922944);   // 16,777,216
  unsigned short* Qb    = (unsigned short*)(ws + 36700160);   // 16,777,216
  unsigned short* Kb    = (unsigned short*)(ws + 53477376);   // 16,777,216
  unsigned short* VTb   = (unsigned short*)(ws + 70254592);   // 16,777,216
  unsigned short* cat   = (unsigned short*)(ws + 87031808);   // 33,554,432
  unsigned*       mp    = (unsigned*)(ws + 120586240);        //  4,194,304
  unsigned*       flag  = (unsigned*)(ws + 124780544);        //         64
  unsigned short* adjb  = (unsigned short*)(ws + 124780608);  // 67,108,864 (optional)

  const int use_adjb = (ws_size >= (size_t)124780608 + 67108864) ? 1 : 0;

  detect_kernel<<<1, 256, 0, stream>>>((const unsigned char*)msk, flag);
  if (use_adjb) {
    prep_small_kernel<<<14336, 256, 0, stream>>>(x, wg, wq, wo, xbf, wcat, woutT);
    gemm_ab_kernel<<<22528, 256, 0, stream>>>(xbf, wcat, xgT, Qb, Kb, VTb,
                                              msk, flag, adj, mp, adjb, 1);
    fused_ca_kernel<<<1536, 256, 0, stream>>>(adjb, xgT, Qb, Kb, VTb, mp, cat);
  } else {
    prep_full_kernel<<<145408, 256, 0, stream>>>(x, wg, wq, wo, msk, flag,
                                                 xbf, wcat, woutT, mp);
    gemm_ab_kernel<<<2048, 256, 0, stream>>>(xbf, wcat, xgT, Qb, Kb, VTb,
                                             msk, flag, adj, mp, adjb, 0);
    gemm_c_f32_kernel<<<512, 256, 0, stream>>>(adj, xgT, cat);
    attn_kernel<<<1024, 256, 0, stream>>>(Qb, Kb, VTb, mp, cat);
  }
  gemm_d_kernel<<<512, 256, 0, stream>>>(cat, woutT, bo, out);
}